// Round 1
// baseline (321.927 us; speedup 1.0000x reference)
//
#include <hip/hip_runtime.h>

#define B_ 2
#define T_ 2048
#define C_ 2048
#define NH_ 16
#define NKV_ 4
#define HD_ 128
#define REP_ (NH_ / NKV_)
#define LDQKV 3072   // fused qkv row stride (elements)

typedef unsigned short u16;
typedef __bf16 bf16x8v __attribute__((ext_vector_type(8)));
typedef float f32x4v __attribute__((ext_vector_type(4)));

__device__ __forceinline__ u16 f2bf(float f) {
    unsigned int u;
    __builtin_memcpy(&u, &f, 4);
    u += 0x7FFFu + ((u >> 16) & 1u);   // RNE
    return (u16)(u >> 16);
}
// pack two fp32 -> two bf16 (round-half-up; bias negligible for P/O tiles)
__device__ __forceinline__ unsigned int pk2(float a, float b) {
    unsigned int ua, ub;
    __builtin_memcpy(&ua, &a, 4);
    __builtin_memcpy(&ub, &b, 4);
    ua += 0x8000u; ub += 0x8000u;
    return (ua >> 16) | (ub & 0xFFFF0000u);
}
__device__ __forceinline__ bf16x8v load8(const u16* p) {
    return *reinterpret_cast<const bf16x8v*>(p);
}
// async global->LDS, 16B per lane. LDS dest must be wave-uniform base + lane*16B.
__device__ __forceinline__ void gl16(const u16* g, u16* l) {
    __builtin_amdgcn_global_load_lds(
        (const __attribute__((address_space(1))) void*)(g),
        (__attribute__((address_space(3))) void*)(l), 16, 0, 0);
}

// ---------------------------------------------------------------------------
// fp32 -> bf16 elementwise convert
// ---------------------------------------------------------------------------
__global__ void cvt_f32_bf16(const float* __restrict__ in, u16* __restrict__ out, int n4) {
    int i = blockIdx.x * blockDim.x + threadIdx.x;
    if (i >= n4) return;
    float4 v = reinterpret_cast<const float4*>(in)[i];
    ushort4 o;
    o.x = f2bf(v.x); o.y = f2bf(v.y); o.z = f2bf(v.z); o.w = f2bf(v.w);
    reinterpret_cast<ushort4*>(out)[i] = o;
}

// ---------------------------------------------------------------------------
// fp32 in [R,Cc] -> bf16 out [Cc,R]; out row stride = R.
// ---------------------------------------------------------------------------
__global__ void xpose_f32_bf16(const float* __restrict__ in, u16* __restrict__ out,
                               int R, int Cc) {
    __shared__ u16 tile[32][33];
    int bx = blockIdx.x * 32, by = blockIdx.y * 32;
    int tx = threadIdx.x, ty = threadIdx.y;  // 32 x 8
    for (int i = 0; i < 32; i += 8)
        tile[ty + i][tx] = f2bf(in[(size_t)(by + ty + i) * Cc + bx + tx]);
    __syncthreads();
    for (int i = 0; i < 32; i += 8)
        out[(size_t)(bx + ty + i) * R + by + tx] = tile[tx][ty + i];
}

// ---------------------------------------------------------------------------
// 256x256-tile GEMM core, BK=64, 512 threads = 8 waves (2M x 4N).
// Double-buffered 128 KiB LDS; counted vmcnt(8) pipeline:
//   prologue: stage(t0->buf0), stage(t1->buf1), vmcnt(8), barrier
//   loop t:   compute buf[t&1]; barrier; stage(t+2->buf[t&1]); vmcnt(8); barrier
// Loads for tile t+1 stay in flight across the entire compute of tile t —
// never drained to 0 in the main loop (T3/T4). Chunk swizzle ^(row&7) on both
// the global source and the ds_read address (T2). setprio around MFMA (T5).
// ---------------------------------------------------------------------------
__device__ __forceinline__ void stage_ab(const u16* gA, const u16* gB,
                                         u16* As, u16* Bs, int tid, int K) {
    u16* lA = As + tid * 8;
    u16* lB = Bs + tid * 8;
#pragma unroll
    for (int j = 0; j < 4; j++) gl16(gA + (size_t)(64 * j) * K, lA + j * 4096);
#pragma unroll
    for (int j = 0; j < 4; j++) gl16(gB + (size_t)(64 * j) * K, lB + j * 4096);
}

// ---------------------------------------------------------------------------
// Fused QKV GEMM: qkv[M,3072] = A[M,2048] @ WqkvT^T.
// RoPE in-epilogue for Q/K cols (partner via shfl_xor lane^1).
// V cols (>=2560) written transposed + key-interleaved into vtb[B][512][T].
// ---------------------------------------------------------------------------
__global__ __launch_bounds__(512, 2) void gemm_qkv(const u16* __restrict__ A,
                                                   const u16* __restrict__ BT,
                                                   u16* __restrict__ Cq,
                                                   u16* __restrict__ vtb,
                                                   const float* __restrict__ cb,
                                                   const float* __restrict__ sb,
                                                   int M, int N, int K) {
    __shared__ __align__(16) u16 As[2][256 * 64];   // 64 KB
    __shared__ __align__(16) u16 Bs[2][256 * 64];   // 64 KB
    int tid = threadIdx.x;
    int lane = tid & 63, wave = tid >> 6;
    int wm = wave >> 2, wn = wave & 3;              // 2M x 4N wave grid
    int m15 = lane & 15, quad = lane >> 4;

    // bijective XCD swizzle (nwg % 8 == 0)
    int nbx = N >> 8;
    int nwg = gridDim.x;
    int bid = blockIdx.x;
    int cpx = nwg >> 3;
    int swz = (bid & 7) * cpx + (bid >> 3);
    int bx = swz % nbx, by = swz / nbx;
    int m0 = by * 256, n0 = bx * 256;

    int r_ = tid >> 3, c_ = tid & 7;
    const u16* gA = A + (size_t)(m0 + r_) * K + (c_ ^ (r_ & 7)) * 8;
    const u16* gB = BT + (size_t)(n0 + r_) * K + (c_ ^ (r_ & 7)) * 8;

    int sw8 = m15 & 7;
    const u16* a0b = &As[0][0] + (wm * 128 + m15) * 64;
    const u16* b0b = &Bs[0][0] + (wn * 64 + m15) * 64;

    f32x4v acc[8][4] = {};

    // prologue: tiles 0 and 1 (issue order pinned so vmcnt(8) => tile0 done)
    stage_ab(gA, gB, As[0], Bs[0], tid, K);
    __builtin_amdgcn_sched_barrier(0);
    stage_ab(gA + 64, gB + 64, As[1], Bs[1], tid, K);
    asm volatile("s_waitcnt vmcnt(8)" ::: "memory");
    __builtin_amdgcn_sched_barrier(0);
    __builtin_amdgcn_s_barrier();

    int NT = K >> 6;
    for (int t = 0; t < NT; t++) {
        const u16* a0 = a0b + (t & 1) * (256 * 64);
        const u16* b0 = b0b + (t & 1) * (256 * 64);
#pragma unroll
        for (int kc = 0; kc < 2; kc++) {
            int co = ((kc * 4 + quad) ^ sw8) * 8;
            bf16x8v bfv[4], af[8];
#pragma unroll
            for (int nt = 0; nt < 4; nt++) bfv[nt] = load8(b0 + nt * 1024 + co);
#pragma unroll
            for (int mt = 0; mt < 8; mt++) af[mt] = load8(a0 + mt * 1024 + co);
            __builtin_amdgcn_s_setprio(1);
#pragma unroll
            for (int mt = 0; mt < 8; mt++)
#pragma unroll
                for (int nt = 0; nt < 4; nt++)
                    acc[mt][nt] = __builtin_amdgcn_mfma_f32_16x16x32_bf16(
                        af[mt], bfv[nt], acc[mt][nt], 0, 0, 0);
            __builtin_amdgcn_s_setprio(0);
        }
        __builtin_amdgcn_s_barrier();           // all waves done reading buf[t&1]
        if (t + 2 < NT) {
            stage_ab(gA + (t + 2) * 64, gB + (t + 2) * 64, As[t & 1], Bs[t & 1], tid, K);
            asm volatile("s_waitcnt vmcnt(8)" ::: "memory");   // tile t+1 resident
        } else {
            asm volatile("s_waitcnt vmcnt(0)" ::: "memory");   // epilogue drain
        }
        __builtin_amdgcn_sched_barrier(0);
        __builtin_amdgcn_s_barrier();
    }

    if (n0 >= 2560) {
        // V region: transposed store, key-interleaved within 32-token windows
#pragma unroll
        for (int mt = 0; mt < 8; mt++)
#pragma unroll
            for (int nt = 0; nt < 4; nt++) {
                int hd = n0 + wn * 64 + nt * 16 + m15 - 2560;
                int mbase = m0 + wm * 128 + mt * 16 + quad * 4;
                int bb = mbase >> 11, tok = mbase & 2047;
                int g = (tok & 31) >> 2;
                int off = (tok & ~31) + ((g & 3) * 8 + (g >> 2) * 4);
                ushort4 pk;
                pk.x = f2bf(acc[mt][nt][0]);
                pk.y = f2bf(acc[mt][nt][1]);
                pk.z = f2bf(acc[mt][nt][2]);
                pk.w = f2bf(acc[mt][nt][3]);
                *reinterpret_cast<ushort4*>(vtb + ((size_t)bb * 512 + hd) * T_ + off) = pk;
            }
    } else {
        // Q/K region: apply RoPE in-register. Pair col c^1 lives in lane^1.
#pragma unroll
        for (int mt = 0; mt < 8; mt++)
#pragma unroll
            for (int nt = 0; nt < 4; nt++) {
                int c = n0 + wn * 64 + nt * 16 + m15;
                int i = (c & 127) >> 1;
                float sgn = (c & 1) ? 1.f : -1.f;
#pragma unroll
                for (int r = 0; r < 4; r++) {
                    int mrow = m0 + wm * 128 + mt * 16 + quad * 4 + r;
                    int tok = mrow & 2047;
                    float cv = cb[tok * 64 + i];
                    float sv = sb[tok * 64 + i];
                    float v = acc[mt][nt][r];
                    float pval = __shfl_xor(v, 1, 64);
                    float outv = fmaf(v, cv, pval * sv * sgn);
                    Cq[(size_t)mrow * N + c] = f2bf(outv);
                }
            }
    }
}

// ---------------------------------------------------------------------------
// Out-proj GEMM (fp32 output), same 256x256 pipelined structure.
// ---------------------------------------------------------------------------
__global__ __launch_bounds__(512, 2) void gemm_out(const u16* __restrict__ A,
                                                   const u16* __restrict__ BT,
                                                   float* __restrict__ C,
                                                   int M, int N, int K) {
    __shared__ __align__(16) u16 As[2][256 * 64];
    __shared__ __align__(16) u16 Bs[2][256 * 64];
    int tid = threadIdx.x;
    int lane = tid & 63, wave = tid >> 6;
    int wm = wave >> 2, wn = wave & 3;
    int m15 = lane & 15, quad = lane >> 4;

    int nbx = N >> 8;
    int nwg = gridDim.x;
    int bid = blockIdx.x;
    int cpx = nwg >> 3;
    int swz = (bid & 7) * cpx + (bid >> 3);
    int bx = swz % nbx, by = swz / nbx;
    int m0 = by * 256, n0 = bx * 256;

    int r_ = tid >> 3, c_ = tid & 7;
    const u16* gA = A + (size_t)(m0 + r_) * K + (c_ ^ (r_ & 7)) * 8;
    const u16* gB = BT + (size_t)(n0 + r_) * K + (c_ ^ (r_ & 7)) * 8;

    int sw8 = m15 & 7;
    const u16* a0b = &As[0][0] + (wm * 128 + m15) * 64;
    const u16* b0b = &Bs[0][0] + (wn * 64 + m15) * 64;

    f32x4v acc[8][4] = {};

    stage_ab(gA, gB, As[0], Bs[0], tid, K);
    __builtin_amdgcn_sched_barrier(0);
    stage_ab(gA + 64, gB + 64, As[1], Bs[1], tid, K);
    asm volatile("s_waitcnt vmcnt(8)" ::: "memory");
    __builtin_amdgcn_sched_barrier(0);
    __builtin_amdgcn_s_barrier();

    int NT = K >> 6;
    for (int t = 0; t < NT; t++) {
        const u16* a0 = a0b + (t & 1) * (256 * 64);
        const u16* b0 = b0b + (t & 1) * (256 * 64);
#pragma unroll
        for (int kc = 0; kc < 2; kc++) {
            int co = ((kc * 4 + quad) ^ sw8) * 8;
            bf16x8v bfv[4], af[8];
#pragma unroll
            for (int nt = 0; nt < 4; nt++) bfv[nt] = load8(b0 + nt * 1024 + co);
#pragma unroll
            for (int mt = 0; mt < 8; mt++) af[mt] = load8(a0 + mt * 1024 + co);
            __builtin_amdgcn_s_setprio(1);
#pragma unroll
            for (int mt = 0; mt < 8; mt++)
#pragma unroll
                for (int nt = 0; nt < 4; nt++)
                    acc[mt][nt] = __builtin_amdgcn_mfma_f32_16x16x32_bf16(
                        af[mt], bfv[nt], acc[mt][nt], 0, 0, 0);
            __builtin_amdgcn_s_setprio(0);
        }
        __builtin_amdgcn_s_barrier();
        if (t + 2 < NT) {
            stage_ab(gA + (t + 2) * 64, gB + (t + 2) * 64, As[t & 1], Bs[t & 1], tid, K);
            asm volatile("s_waitcnt vmcnt(8)" ::: "memory");
        } else {
            asm volatile("s_waitcnt vmcnt(0)" ::: "memory");
        }
        __builtin_amdgcn_sched_barrier(0);
        __builtin_amdgcn_s_barrier();
    }

#pragma unroll
    for (int mt = 0; mt < 8; mt++)
#pragma unroll
        for (int nt = 0; nt < 4; nt++) {
            int c = n0 + wn * 64 + nt * 16 + m15;
#pragma unroll
            for (int r = 0; r < 4; r++) {
                int mrow = m0 + wm * 128 + mt * 16 + quad * 4 + r;
                C[(size_t)mrow * N + c] = acc[mt][nt][r];
            }
        }
}

// ---------------------------------------------------------------------------
// Flash attention v4 (unchanged this round): S^T orientation (K*Q^T) so P
// feeds PV as a B-operand straight from registers; fixed-max softmax;
// 128-key LDS tiles (K+V 64 KB); balanced q-tile pairs {x, 31-x}.
// ---------------------------------------------------------------------------
__device__ __forceinline__ void stage_k128(const u16* kB, u16* Kl, int kt, int tid) {
    int keyc = tid >> 4, ch = tid & 15;
    const u16* g = kB + (size_t)(kt + keyc) * LDQKV + (ch ^ keyc) * 8;
    u16* l = Kl + tid * 8;
    for (int j = 0; j < 8; j++) {
        gl16(g, l);
        g += (size_t)16 * LDQKV;
        l += 2048;
    }
}
__device__ __forceinline__ void stage_v128(const u16* vB, u16* Vl, int kt, int tid) {
    int hdc = tid >> 4, ch = tid & 15;
    const u16* g = vB + (size_t)hdc * T_ + kt + (ch ^ hdc) * 8;
    u16* l = Vl + tid * 8;
    for (int j = 0; j < 8; j++) {
        gl16(g, l);
        g += (size_t)16 * T_;
        l += 2048;
    }
}

__global__ __launch_bounds__(256) void flash_k(const u16* __restrict__ qkv,
                                               const u16* __restrict__ vtb,
                                               u16* __restrict__ yb) {
    __shared__ __align__(16) u16 Kl[128 * 128];    // 32 KB
    __shared__ __align__(16) u16 Vl[128 * 128];    // 32 KB -> 64 KB: 2 blocks/CU
    int h = blockIdx.y, b = blockIdx.z;
    int kv = h / REP_;
    int tid = threadIdx.x;
    int lane = tid & 63, wave = tid >> 6;
    int m15 = lane & 15, quad = lane >> 4;
    const u16* kB = qkv + (size_t)b * T_ * LDQKV + 2048 + kv * HD_;
    const u16* vB = vtb + ((size_t)(b * NKV_ + kv)) * HD_ * T_;
    const float scale2 = 0.1275173723f;  // 1/sqrt(128) * log2(e)
    const float M0b = 8.0f;              // fixed max (exp2 domain)
    const float NEG = -3.0e38f;

    for (int p = 0; p < 2; p++) {
        int qt = (p == 0) ? (int)blockIdx.x : (31 - (int)blockIdx.x);
        int qt0 = qt * 64;
        int qrow = qt0 + wave * 16;
        int q_i = qrow + m15;            // this lane's query (col of S^T)
        const u16* qp = qkv + (size_t)(b * T_ + q_i) * LDQKV + h * HD_ + quad * 8;
        bf16x8v qf[4];
        for (int kc = 0; kc < 4; kc++) qf[kc] = load8(qp + kc * 32);
        f32x4v o[8] = {};
        f32x4v lacc = {};

        int iters = qt0 / 128 + 1;
        for (int it = 0; it < iters; it++) {
            int kt = it * 128;
            __syncthreads();                     // prior LDS reads done
            stage_k128(kB, Kl, kt, tid);
            stage_v128(vB, Vl, kt, tid);
            __syncthreads();                     // drain staging
            // S^T = K Q^T: rows = keys (quad*4+r), cols = q (lane&15)
            f32x4v s4[8];
            for (int nt = 0; nt < 8; nt++) s4[nt] = (f32x4v){0.f, 0.f, 0.f, 0.f};
            for (int nt = 0; nt < 8; nt++) {
                const u16* kls = Kl + (nt * 16 + m15) * 128;
                for (int kc = 0; kc < 4; kc++)
                    s4[nt] = __builtin_amdgcn_mfma_f32_16x16x32_bf16(
                        load8(kls + (((kc * 4 + quad) ^ m15) * 8)), qf[kc], s4[nt], 0, 0, 0);
            }
            // causal mask (last iter only): key > q
            if (kt + 128 > qt0) {
                for (int nt = 0; nt < 8; nt++) {
                    int key = kt + nt * 16 + quad * 4;
                    for (int r = 0; r < 4; r++)
                        if (key + r > q_i) s4[nt][r] = NEG;
                }
            }
            // fixed-max exp2 + l accumulation (no shuffles, no rescale)
            for (int nt = 0; nt < 8; nt++) {
                for (int r = 0; r < 4; r++)
                    s4[nt][r] = exp2f(fmaf(s4[nt][r], scale2, -M0b));
                lacc += s4[nt];
            }
            // PV: P packed to bf16 B-frags in-register; V A-frags from LDS
            for (int c = 0; c < 4; c++) {
                unsigned int w[4];
                w[0] = pk2(s4[2 * c][0], s4[2 * c][1]);
                w[1] = pk2(s4[2 * c][2], s4[2 * c][3]);
                w[2] = pk2(s4[2 * c + 1][0], s4[2 * c + 1][1]);
                w[3] = pk2(s4[2 * c + 1][2], s4[2 * c + 1][3]);
                bf16x8v pf;
                __builtin_memcpy(&pf, w, 16);
                for (int dt = 0; dt < 8; dt++) {
                    const u16* vls = Vl + (dt * 16 + m15) * 128;
                    o[dt] = __builtin_amdgcn_mfma_f32_16x16x32_bf16(
                        load8(vls + (((c * 4 + quad) ^ m15) * 8)), pf, o[dt], 0, 0, 0);
                }
            }
        }
        // epilogue: l = sum over this lane's 4 partials, then across quads
        float l = lacc[0] + lacc[1] + lacc[2] + lacc[3];
        l += __shfl_xor(l, 16, 64);
        l += __shfl_xor(l, 32, 64);
        float inv = 1.f / l;
        u16* yp = yb + (size_t)(b * T_ + q_i) * C_ + h * HD_ + quad * 4;
        for (int dt = 0; dt < 8; dt++) {
            ushort4 pk;
            pk.x = f2bf(o[dt][0] * inv);
            pk.y = f2bf(o[dt][1] * inv);
            pk.z = f2bf(o[dt][2] * inv);
            pk.w = f2bf(o[dt][3] * inv);
            *reinterpret_cast<ushort4*>(yp + dt * 16) = pk;
        }
    }
}

// ---------------------------------------------------------------------------
extern "C" void kernel_launch(void* const* d_in, const int* in_sizes, int n_in,
                              void* d_out, int out_size, void* d_ws, size_t ws_size,
                              hipStream_t stream) {
    const float* x  = (const float*)d_in[0];
    const float* Wq = (const float*)d_in[1];
    const float* Wk = (const float*)d_in[2];
    const float* Wv = (const float*)d_in[3];
    const float* Wo = (const float*)d_in[4];
    const float* fc = (const float*)d_in[5];
    const float* fs = (const float*)d_in[6];
    float* out = (float*)d_out;

    char* ws = (char*)d_ws;
    u16* WqkvT = (u16*)(ws);                    // [3072][2048] bf16, 12.58 MB
    u16* WoT   = (u16*)(ws + 12582912);         // [2048][2048] bf16,  8.39 MB
    u16* xb    = (u16*)(ws + 20971520);         // [4096][2048] bf16, 16.78 MB
    u16* qkvb  = (u16*)(ws + 37748736);         // [4096][3072] bf16, 25.17 MB
    u16* vtb   = (u16*)(ws + 62914560);         // [B][512][T]  bf16,  4.19 MB
    u16* yb    = (u16*)(ws + 67108864);         // [4096][2048] bf16, 16.78 MB

    const int M = B_ * T_;

    int n4 = (M * C_) / 4;
    cvt_f32_bf16<<<n4 / 256, 256, 0, stream>>>(x, xb, n4);

    dim3 tb(32, 8);
    xpose_f32_bf16<<<dim3(C_ / 32, C_ / 32), tb, 0, stream>>>(Wq, WqkvT, C_, C_);
    xpose_f32_bf16<<<dim3((NKV_ * HD_) / 32, C_ / 32), tb, 0, stream>>>(Wk, WqkvT + 2048 * 2048, C_, NKV_ * HD_);
    xpose_f32_bf16<<<dim3((NKV_ * HD_) / 32, C_ / 32), tb, 0, stream>>>(Wv, WqkvT + 2560 * 2048, C_, NKV_ * HD_);
    xpose_f32_bf16<<<dim3(C_ / 32, C_ / 32), tb, 0, stream>>>(Wo, WoT, C_, C_);

    // fused QKV projection + in-epilogue RoPE; V pre-transposed into vtb
    // grid = (3072/256)*(4096/256) = 192 workgroups (%8==0 for XCD swizzle)
    gemm_qkv<<<dim3((LDQKV / 256) * (M / 256)), 512, 0, stream>>>(xb, WqkvT, qkvb, vtb, fc, fs, M, LDQKV, C_);

    flash_k<<<dim3(T_ / 128, NH_, B_), 256, 0, stream>>>(qkvb, vtb, yb);

    // grid = (2048/256)*(4096/256) = 128 workgroups
    gemm_out<<<dim3((C_ / 256) * (M / 256)), 512, 0, stream>>>(yb, WoT, out, M, C_, C_);
}

// Round 2
// 297.641 us; speedup vs baseline: 1.0816x; 1.0816x over previous
//
#include <hip/hip_runtime.h>

#define B_ 2
#define T_ 2048
#define C_ 2048
#define NH_ 16
#define NKV_ 4
#define HD_ 128
#define REP_ (NH_ / NKV_)
#define LDQKV 3072   // fused qkv row stride (elements)

typedef unsigned short u16;
typedef __bf16 bf16x8v __attribute__((ext_vector_type(8)));
typedef float f32x4v __attribute__((ext_vector_type(4)));

__device__ __forceinline__ u16 f2bf(float f) {
    unsigned int u;
    __builtin_memcpy(&u, &f, 4);
    u += 0x7FFFu + ((u >> 16) & 1u);   // RNE
    return (u16)(u >> 16);
}
__device__ __forceinline__ unsigned int pk2(float a, float b) {
    unsigned int ua, ub;
    __builtin_memcpy(&ua, &a, 4);
    __builtin_memcpy(&ub, &b, 4);
    ua += 0x8000u; ub += 0x8000u;
    return (ua >> 16) | (ub & 0xFFFF0000u);
}
__device__ __forceinline__ bf16x8v load8(const u16* p) {
    return *reinterpret_cast<const bf16x8v*>(p);
}
// async global->LDS, 16B per lane. LDS dest must be wave-uniform base + lane*16B.
__device__ __forceinline__ void gl16(const u16* g, u16* l) {
    __builtin_amdgcn_global_load_lds(
        (const __attribute__((address_space(1))) void*)(g),
        (__attribute__((address_space(3))) void*)(l), 16, 0, 0);
}
// stage one 128-row x 64-col bf16 half-tile: 2 gl16/thread (512 threads)
__device__ __forceinline__ void stg(const u16* g, u16* l, int tid, int K) {
    gl16(g, l + tid * 8);
    gl16(g + (size_t)64 * K, l + 4096 + tid * 8);
}
#define BAR()      __builtin_amdgcn_s_barrier()
#define LGKM0()    asm volatile("s_waitcnt lgkmcnt(0)" ::: "memory")
#define SCHED0()   __builtin_amdgcn_sched_barrier(0)
#define PRIO(x)    __builtin_amdgcn_s_setprio(x)

// ---------------------------------------------------------------------------
// fp32 -> bf16 elementwise convert
// ---------------------------------------------------------------------------
__global__ void cvt_f32_bf16(const float* __restrict__ in, u16* __restrict__ out, int n4) {
    int i = blockIdx.x * blockDim.x + threadIdx.x;
    if (i >= n4) return;
    float4 v = reinterpret_cast<const float4*>(in)[i];
    ushort4 o;
    o.x = f2bf(v.x); o.y = f2bf(v.y); o.z = f2bf(v.z); o.w = f2bf(v.w);
    reinterpret_cast<ushort4*>(out)[i] = o;
}

// ---------------------------------------------------------------------------
// fp32 in [R,Cc] -> bf16 out [Cc,R]; out row stride = R.
// ---------------------------------------------------------------------------
__global__ void xpose_f32_bf16(const float* __restrict__ in, u16* __restrict__ out,
                               int R, int Cc) {
    __shared__ u16 tile[32][33];
    int bx = blockIdx.x * 32, by = blockIdx.y * 32;
    int tx = threadIdx.x, ty = threadIdx.y;  // 32 x 8
    for (int i = 0; i < 32; i += 8)
        tile[ty + i][tx] = f2bf(in[(size_t)(by + ty + i) * Cc + bx + tx]);
    __syncthreads();
    for (int i = 0; i < 32; i += 8)
        out[(size_t)(bx + ty + i) * R + by + tx] = tile[tx][ty + i];
}

// ---------------------------------------------------------------------------
// Fused QKV GEMM: 256x256 tile, BK=64, 512 thr = 8 waves (2M x 4N),
// m201-style 8-phase schedule (4 phases/K-tile, 16 MFMA each):
//   ph1 Q1(mt0-3,nt0-1): 12 ds_read | stage A-h0(t+1)
//   ph2 Q2(mt0-3,nt2-3):  4 ds_read | stage A-h1(t+1)
//   ph3 Q3(mt4-7,nt0-1):  8 ds_read | stage B-h0(t+2)
//   ph4 Q4(mt4-7,nt2-3):  0 ds_read | stage B-h1(t+2) + vmcnt(4)
// Overwrite safety: A-halves of tile t last read ph3, B-halves ph2; all
// stages land >=1 barrier after the last read of the region they replace.
// vmcnt(4) once per tile (counted, never 0 in main loop).
// ---------------------------------------------------------------------------
__global__ __launch_bounds__(512, 2) void gemm_qkv(const u16* __restrict__ A,
                                                   const u16* __restrict__ BT,
                                                   u16* __restrict__ Cq,
                                                   u16* __restrict__ vtb,
                                                   const float* __restrict__ cb,
                                                   const float* __restrict__ sb,
                                                   int M, int N, int K) {
    __shared__ __align__(16) u16 As[2][2][8192];   // [dbuf][half: rows 0-127/128-255][128x64]
    __shared__ __align__(16) u16 Bs[2][2][8192];   // [dbuf][half: cols 0-127/128-255]
    int tid = threadIdx.x;
    int lane = tid & 63, wave = tid >> 6;
    int wm = wave >> 2, wn = wave & 3;              // 2M x 4N wave grid
    int m15 = lane & 15, quad = lane >> 4;

    // bijective XCD swizzle (grid % 8 == 0)
    int nbx = N >> 8;
    int bid = blockIdx.x, cpx = gridDim.x >> 3;
    int swz = (bid & 7) * cpx + (bid >> 3);
    int m0 = (swz / nbx) * 256, n0 = (swz % nbx) * 256;

    // staging source: row r = tid>>3 (64 rows/gl16), chunk pre-swizzled ^(r&7)
    const u16* gA0 = A + (size_t)(m0 + (tid >> 3)) * K + (((tid & 7) ^ ((tid >> 3) & 7)) * 8);
    const u16* gB0 = BT + (size_t)(n0 + (tid >> 3)) * K + (((tid & 7) ^ ((tid >> 3) & 7)) * 8);

    int sw8 = m15 & 7;
    int co0 = (quad ^ sw8) * 8;          // kc=0 chunk (swizzled read)
    int co1 = ((4 + quad) ^ sw8) * 8;    // kc=1 chunk
    const u16* aB = &As[0][0][0] + wm * 8192 + m15 * 64;                     // + d*16384 + mt*1024
    const u16* bB = &Bs[0][0][0] + (wn >> 1) * 8192 + ((wn & 1) * 64 + m15) * 64;

    f32x4v acc[8][4] = {};
    int NT = K >> 6;

    // prologue stream: B0(0) B1(0) A0(0) A1(0) B0(1) B1(1); vmcnt(4) => tile 0 resident
    stg(gB0, &Bs[0][0][0], tid, K);
    stg(gB0 + (size_t)128 * K, &Bs[0][1][0], tid, K);
    stg(gA0, &As[0][0][0], tid, K);
    stg(gA0 + (size_t)128 * K, &As[0][1][0], tid, K);
    stg(gB0 + 64, &Bs[1][0][0], tid, K);
    stg(gB0 + (size_t)128 * K + 64, &Bs[1][1][0], tid, K);
    asm volatile("s_waitcnt vmcnt(4)" ::: "memory");
    SCHED0();
    BAR();

    for (int t = 0; t < NT; t++) {
        int d = t & 1;
        const u16* aT = aB + d * 16384;
        const u16* bT = bB + d * 16384;
        bf16x8v a0[4][2], a1[4][2], b0[2][2], b1[2][2];

        // ---- phase 1: Q1
#pragma unroll
        for (int mt = 0; mt < 4; mt++) {
            a0[mt][0] = load8(aT + mt * 1024 + co0);
            a0[mt][1] = load8(aT + mt * 1024 + co1);
        }
#pragma unroll
        for (int nt = 0; nt < 2; nt++) {
            b0[nt][0] = load8(bT + nt * 1024 + co0);
            b0[nt][1] = load8(bT + nt * 1024 + co1);
        }
        if (t + 1 < NT) stg(gA0 + (t + 1) * 64, &As[1 - d][0][0], tid, K);
        BAR(); LGKM0(); SCHED0(); PRIO(1);
#pragma unroll
        for (int kc = 0; kc < 2; kc++)
#pragma unroll
            for (int mt = 0; mt < 4; mt++)
#pragma unroll
                for (int nt = 0; nt < 2; nt++)
                    acc[mt][nt] = __builtin_amdgcn_mfma_f32_16x16x32_bf16(
                        a0[mt][kc], b0[nt][kc], acc[mt][nt], 0, 0, 0);
        PRIO(0); BAR();

        // ---- phase 2: Q2
#pragma unroll
        for (int nt = 0; nt < 2; nt++) {
            b1[nt][0] = load8(bT + (nt + 2) * 1024 + co0);
            b1[nt][1] = load8(bT + (nt + 2) * 1024 + co1);
        }
        if (t + 1 < NT) stg(gA0 + (size_t)128 * K + (t + 1) * 64, &As[1 - d][1][0], tid, K);
        BAR(); LGKM0(); SCHED0(); PRIO(1);
#pragma unroll
        for (int kc = 0; kc < 2; kc++)
#pragma unroll
            for (int mt = 0; mt < 4; mt++)
#pragma unroll
                for (int nt = 0; nt < 2; nt++)
                    acc[mt][nt + 2] = __builtin_amdgcn_mfma_f32_16x16x32_bf16(
                        a0[mt][kc], b1[nt][kc], acc[mt][nt + 2], 0, 0, 0);
        PRIO(0); BAR();

        // ---- phase 3: Q3
#pragma unroll
        for (int mt = 0; mt < 4; mt++) {
            a1[mt][0] = load8(aT + (mt + 4) * 1024 + co0);
            a1[mt][1] = load8(aT + (mt + 4) * 1024 + co1);
        }
        if (t + 2 < NT) stg(gB0 + (t + 2) * 64, &Bs[d][0][0], tid, K);
        BAR(); LGKM0(); SCHED0(); PRIO(1);
#pragma unroll
        for (int kc = 0; kc < 2; kc++)
#pragma unroll
            for (int mt = 0; mt < 4; mt++)
#pragma unroll
                for (int nt = 0; nt < 2; nt++)
                    acc[mt + 4][nt] = __builtin_amdgcn_mfma_f32_16x16x32_bf16(
                        a1[mt][kc], b0[nt][kc], acc[mt + 4][nt], 0, 0, 0);
        PRIO(0); BAR();

        // ---- phase 4: Q4 (regs only)
        if (t + 2 < NT) stg(gB0 + (size_t)128 * K + (t + 2) * 64, &Bs[d][1][0], tid, K);
        BAR(); PRIO(1);
#pragma unroll
        for (int kc = 0; kc < 2; kc++)
#pragma unroll
            for (int mt = 0; mt < 4; mt++)
#pragma unroll
                for (int nt = 0; nt < 2; nt++)
                    acc[mt + 4][nt + 2] = __builtin_amdgcn_mfma_f32_16x16x32_bf16(
                        a1[mt][kc], b1[nt][kc], acc[mt + 4][nt + 2], 0, 0, 0);
        PRIO(0);
        if (t + 2 < NT) { asm volatile("s_waitcnt vmcnt(4)" ::: "memory"); }
        else            { asm volatile("s_waitcnt vmcnt(0)" ::: "memory"); }
        SCHED0();
        BAR();
    }

    if (n0 >= 2560) {
        // V region: transposed store, key-interleaved within 32-token windows
#pragma unroll
        for (int mt = 0; mt < 8; mt++)
#pragma unroll
            for (int nt = 0; nt < 4; nt++) {
                int hd = n0 + wn * 64 + nt * 16 + m15 - 2560;
                int mbase = m0 + wm * 128 + mt * 16 + quad * 4;
                int bb = mbase >> 11, tok = mbase & 2047;
                int g = (tok & 31) >> 2;
                int off = (tok & ~31) + ((g & 3) * 8 + (g >> 2) * 4);
                ushort4 pk;
                pk.x = f2bf(acc[mt][nt][0]);
                pk.y = f2bf(acc[mt][nt][1]);
                pk.z = f2bf(acc[mt][nt][2]);
                pk.w = f2bf(acc[mt][nt][3]);
                *reinterpret_cast<ushort4*>(vtb + ((size_t)bb * 512 + hd) * T_ + off) = pk;
            }
    } else {
        // Q/K region: apply RoPE in-register. Pair col c^1 lives in lane^1.
#pragma unroll
        for (int mt = 0; mt < 8; mt++)
#pragma unroll
            for (int nt = 0; nt < 4; nt++) {
                int c = n0 + wn * 64 + nt * 16 + m15;
                int i = (c & 127) >> 1;
                float sgn = (c & 1) ? 1.f : -1.f;
#pragma unroll
                for (int r = 0; r < 4; r++) {
                    int mrow = m0 + wm * 128 + mt * 16 + quad * 4 + r;
                    int tok = mrow & 2047;
                    float cv = cb[tok * 64 + i];
                    float sv = sb[tok * 64 + i];
                    float v = acc[mt][nt][r];
                    float pval = __shfl_xor(v, 1, 64);
                    float outv = fmaf(v, cv, pval * sv * sgn);
                    Cq[(size_t)mrow * N + c] = f2bf(outv);
                }
            }
    }
}

// ---------------------------------------------------------------------------
// Out-proj GEMM (fp32 out): 128x256 tile (grid 256 WGs = full machine),
// same 8-phase scheme, 8 MFMA/phase, acc[4][4], 96 KiB LDS.
//   ph1 Q1(mt0-1,nt0-1): 8 ds_read | stage A(t+1)
//   ph2 Q2(mt0-1,nt2-3): 4 ds_read | -
//   ph3 Q3(mt2-3,nt0-1): 4 ds_read | stage B-h0(t+2)
//   ph4 Q4(mt2-3,nt2-3): 0 ds_read | stage B-h1(t+2) + vmcnt(4)
// ---------------------------------------------------------------------------
__global__ __launch_bounds__(512, 2) void gemm_out(const u16* __restrict__ A,
                                                   const u16* __restrict__ BT,
                                                   float* __restrict__ C,
                                                   int M, int N, int K) {
    __shared__ __align__(16) u16 As2[2][8192];      // [dbuf][128 rows x 64]
    __shared__ __align__(16) u16 Bs2[2][2][8192];   // [dbuf][col-half][128 x 64]
    int tid = threadIdx.x;
    int lane = tid & 63, wave = tid >> 6;
    int wm = wave >> 2, wn = wave & 3;              // per-wave 64 rows x 64 cols
    int m15 = lane & 15, quad = lane >> 4;

    int nbx = N >> 8;                               // = 8
    int bid = blockIdx.x, cpx = gridDim.x >> 3;
    int swz = (bid & 7) * cpx + (bid >> 3);
    int m0 = (swz / nbx) * 128, n0 = (swz % nbx) * 256;

    const u16* gA0 = A + (size_t)(m0 + (tid >> 3)) * K + (((tid & 7) ^ ((tid >> 3) & 7)) * 8);
    const u16* gB0 = BT + (size_t)(n0 + (tid >> 3)) * K + (((tid & 7) ^ ((tid >> 3) & 7)) * 8);

    int sw8 = m15 & 7;
    int co0 = (quad ^ sw8) * 8;
    int co1 = ((4 + quad) ^ sw8) * 8;
    const u16* aB = &As2[0][0] + (wm * 64 + m15) * 64;                       // + d*8192 + mt*1024
    const u16* bB = &Bs2[0][0][0] + (wn >> 1) * 8192 + ((wn & 1) * 64 + m15) * 64;

    f32x4v acc[4][4] = {};
    int NT = K >> 6;

    // prologue stream: B0(0) B1(0) A(0) B0(1) B1(1); vmcnt(4) => tile 0 resident
    stg(gB0, &Bs2[0][0][0], tid, K);
    stg(gB0 + (size_t)128 * K, &Bs2[0][1][0], tid, K);
    stg(gA0, &As2[0][0], tid, K);
    stg(gB0 + 64, &Bs2[1][0][0], tid, K);
    stg(gB0 + (size_t)128 * K + 64, &Bs2[1][1][0], tid, K);
    asm volatile("s_waitcnt vmcnt(4)" ::: "memory");
    SCHED0();
    BAR();

    for (int t = 0; t < NT; t++) {
        int d = t & 1;
        const u16* aT = aB + d * 8192;
        const u16* bT = bB + d * 16384;
        bf16x8v a0[2][2], a1[2][2], b0[2][2], b1[2][2];

        // ---- phase 1: Q1
#pragma unroll
        for (int mt = 0; mt < 2; mt++) {
            a0[mt][0] = load8(aT + mt * 1024 + co0);
            a0[mt][1] = load8(aT + mt * 1024 + co1);
        }
#pragma unroll
        for (int nt = 0; nt < 2; nt++) {
            b0[nt][0] = load8(bT + nt * 1024 + co0);
            b0[nt][1] = load8(bT + nt * 1024 + co1);
        }
        if (t + 1 < NT) stg(gA0 + (t + 1) * 64, &As2[1 - d][0], tid, K);
        BAR(); LGKM0(); SCHED0(); PRIO(1);
#pragma unroll
        for (int kc = 0; kc < 2; kc++)
#pragma unroll
            for (int mt = 0; mt < 2; mt++)
#pragma unroll
                for (int nt = 0; nt < 2; nt++)
                    acc[mt][nt] = __builtin_amdgcn_mfma_f32_16x16x32_bf16(
                        a0[mt][kc], b0[nt][kc], acc[mt][nt], 0, 0, 0);
        PRIO(0); BAR();

        // ---- phase 2: Q2
#pragma unroll
        for (int nt = 0; nt < 2; nt++) {
            b1[nt][0] = load8(bT + (nt + 2) * 1024 + co0);
            b1[nt][1] = load8(bT + (nt + 2) * 1024 + co1);
        }
        BAR(); LGKM0(); SCHED0(); PRIO(1);
#pragma unroll
        for (int kc = 0; kc < 2; kc++)
#pragma unroll
            for (int mt = 0; mt < 2; mt++)
#pragma unroll
                for (int nt = 0; nt < 2; nt++)
                    acc[mt][nt + 2] = __builtin_amdgcn_mfma_f32_16x16x32_bf16(
                        a0[mt][kc], b1[nt][kc], acc[mt][nt + 2], 0, 0, 0);
        PRIO(0); BAR();

        // ---- phase 3: Q3
#pragma unroll
        for (int mt = 0; mt < 2; mt++) {
            a1[mt][0] = load8(aT + (mt + 2) * 1024 + co0);
            a1[mt][1] = load8(aT + (mt + 2) * 1024 + co1);
        }
        if (t + 2 < NT) stg(gB0 + (t + 2) * 64, &Bs2[d][0][0], tid, K);
        BAR(); LGKM0(); SCHED0(); PRIO(1);
#pragma unroll
        for (int kc = 0; kc < 2; kc++)
#pragma unroll
            for (int mt = 0; mt < 2; mt++)
#pragma unroll
                for (int nt = 0; nt < 2; nt++)
                    acc[mt + 2][nt] = __builtin_amdgcn_mfma_f32_16x16x32_bf16(
                        a1[mt][kc], b0[nt][kc], acc[mt + 2][nt], 0, 0, 0);
        PRIO(0); BAR();

        // ---- phase 4: Q4 (regs only)
        if (t + 2 < NT) stg(gB0 + (size_t)128 * K + (t + 2) * 64, &Bs2[d][1][0], tid, K);
        BAR(); PRIO(1);
#pragma unroll
        for (int kc = 0; kc < 2; kc++)
#pragma unroll
            for (int mt = 0; mt < 2; mt++)
#pragma unroll
                for (int nt = 0; nt < 2; nt++)
                    acc[mt + 2][nt + 2] = __builtin_amdgcn_mfma_f32_16x16x32_bf16(
                        a1[mt][kc], b1[nt][kc], acc[mt + 2][nt + 2], 0, 0, 0);
        PRIO(0);
        if (t + 2 < NT) { asm volatile("s_waitcnt vmcnt(4)" ::: "memory"); }
        else            { asm volatile("s_waitcnt vmcnt(0)" ::: "memory"); }
        SCHED0();
        BAR();
    }

#pragma unroll
    for (int mt = 0; mt < 4; mt++)
#pragma unroll
        for (int nt = 0; nt < 4; nt++) {
            int c = n0 + wn * 64 + nt * 16 + m15;
#pragma unroll
            for (int r = 0; r < 4; r++) {
                int mrow = m0 + wm * 64 + mt * 16 + quad * 4 + r;
                C[(size_t)mrow * N + c] = acc[mt][nt][r];
            }
        }
}

// ---------------------------------------------------------------------------
// Flash attention v4 (unchanged this round): S^T orientation (K*Q^T) so P
// feeds PV as a B-operand straight from registers; fixed-max softmax;
// 128-key LDS tiles (K+V 64 KB); balanced q-tile pairs {x, 31-x}.
// ---------------------------------------------------------------------------
__device__ __forceinline__ void stage_k128(const u16* kB, u16* Kl, int kt, int tid) {
    int keyc = tid >> 4, ch = tid & 15;
    const u16* g = kB + (size_t)(kt + keyc) * LDQKV + (ch ^ keyc) * 8;
    u16* l = Kl + tid * 8;
    for (int j = 0; j < 8; j++) {
        gl16(g, l);
        g += (size_t)16 * LDQKV;
        l += 2048;
    }
}
__device__ __forceinline__ void stage_v128(const u16* vB, u16* Vl, int kt, int tid) {
    int hdc = tid >> 4, ch = tid & 15;
    const u16* g = vB + (size_t)hdc * T_ + kt + (ch ^ hdc) * 8;
    u16* l = Vl + tid * 8;
    for (int j = 0; j < 8; j++) {
        gl16(g, l);
        g += (size_t)16 * T_;
        l += 2048;
    }
}

__global__ __launch_bounds__(256) void flash_k(const u16* __restrict__ qkv,
                                               const u16* __restrict__ vtb,
                                               u16* __restrict__ yb) {
    __shared__ __align__(16) u16 Kl[128 * 128];    // 32 KB
    __shared__ __align__(16) u16 Vl[128 * 128];    // 32 KB -> 64 KB: 2 blocks/CU
    int h = blockIdx.y, b = blockIdx.z;
    int kv = h / REP_;
    int tid = threadIdx.x;
    int lane = tid & 63, wave = tid >> 6;
    int m15 = lane & 15, quad = lane >> 4;
    const u16* kB = qkv + (size_t)b * T_ * LDQKV + 2048 + kv * HD_;
    const u16* vB = vtb + ((size_t)(b * NKV_ + kv)) * HD_ * T_;
    const float scale2 = 0.1275173723f;  // 1/sqrt(128) * log2(e)
    const float M0b = 8.0f;              // fixed max (exp2 domain)
    const float NEG = -3.0e38f;

    for (int p = 0; p < 2; p++) {
        int qt = (p == 0) ? (int)blockIdx.x : (31 - (int)blockIdx.x);
        int qt0 = qt * 64;
        int qrow = qt0 + wave * 16;
        int q_i = qrow + m15;            // this lane's query (col of S^T)
        const u16* qp = qkv + (size_t)(b * T_ + q_i) * LDQKV + h * HD_ + quad * 8;
        bf16x8v qf[4];
        for (int kc = 0; kc < 4; kc++) qf[kc] = load8(qp + kc * 32);
        f32x4v o[8] = {};
        f32x4v lacc = {};

        int iters = qt0 / 128 + 1;
        for (int it = 0; it < iters; it++) {
            int kt = it * 128;
            __syncthreads();                     // prior LDS reads done
            stage_k128(kB, Kl, kt, tid);
            stage_v128(vB, Vl, kt, tid);
            __syncthreads();                     // drain staging
            // S^T = K Q^T: rows = keys (quad*4+r), cols = q (lane&15)
            f32x4v s4[8];
            for (int nt = 0; nt < 8; nt++) s4[nt] = (f32x4v){0.f, 0.f, 0.f, 0.f};
            for (int nt = 0; nt < 8; nt++) {
                const u16* kls = Kl + (nt * 16 + m15) * 128;
                for (int kc = 0; kc < 4; kc++)
                    s4[nt] = __builtin_amdgcn_mfma_f32_16x16x32_bf16(
                        load8(kls + (((kc * 4 + quad) ^ m15) * 8)), qf[kc], s4[nt], 0, 0, 0);
            }
            // causal mask (last iter only): key > q
            if (kt + 128 > qt0) {
                for (int nt = 0; nt < 8; nt++) {
                    int key = kt + nt * 16 + quad * 4;
                    for (int r = 0; r < 4; r++)
                        if (key + r > q_i) s4[nt][r] = NEG;
                }
            }
            // fixed-max exp2 + l accumulation (no shuffles, no rescale)
            for (int nt = 0; nt < 8; nt++) {
                for (int r = 0; r < 4; r++)
                    s4[nt][r] = exp2f(fmaf(s4[nt][r], scale2, -M0b));
                lacc += s4[nt];
            }
            // PV: P packed to bf16 B-frags in-register; V A-frags from LDS
            for (int c = 0; c < 4; c++) {
                unsigned int w[4];
                w[0] = pk2(s4[2 * c][0], s4[2 * c][1]);
                w[1] = pk2(s4[2 * c][2], s4[2 * c][3]);
                w[2] = pk2(s4[2 * c + 1][0], s4[2 * c + 1][1]);
                w[3] = pk2(s4[2 * c + 1][2], s4[2 * c + 1][3]);
                bf16x8v pf;
                __builtin_memcpy(&pf, w, 16);
                for (int dt = 0; dt < 8; dt++) {
                    const u16* vls = Vl + (dt * 16 + m15) * 128;
                    o[dt] = __builtin_amdgcn_mfma_f32_16x16x32_bf16(
                        load8(vls + (((c * 4 + quad) ^ m15) * 8)), pf, o[dt], 0, 0, 0);
                }
            }
        }
        // epilogue: l = sum over this lane's 4 partials, then across quads
        float l = lacc[0] + lacc[1] + lacc[2] + lacc[3];
        l += __shfl_xor(l, 16, 64);
        l += __shfl_xor(l, 32, 64);
        float inv = 1.f / l;
        u16* yp = yb + (size_t)(b * T_ + q_i) * C_ + h * HD_ + quad * 4;
        for (int dt = 0; dt < 8; dt++) {
            ushort4 pk;
            pk.x = f2bf(o[dt][0] * inv);
            pk.y = f2bf(o[dt][1] * inv);
            pk.z = f2bf(o[dt][2] * inv);
            pk.w = f2bf(o[dt][3] * inv);
            *reinterpret_cast<ushort4*>(yp + dt * 16) = pk;
        }
    }
}

// ---------------------------------------------------------------------------
extern "C" void kernel_launch(void* const* d_in, const int* in_sizes, int n_in,
                              void* d_out, int out_size, void* d_ws, size_t ws_size,
                              hipStream_t stream) {
    const float* x  = (const float*)d_in[0];
    const float* Wq = (const float*)d_in[1];
    const float* Wk = (const float*)d_in[2];
    const float* Wv = (const float*)d_in[3];
    const float* Wo = (const float*)d_in[4];
    const float* fc = (const float*)d_in[5];
    const float* fs = (const float*)d_in[6];
    float* out = (float*)d_out;

    char* ws = (char*)d_ws;
    u16* WqkvT = (u16*)(ws);                    // [3072][2048] bf16, 12.58 MB
    u16* WoT   = (u16*)(ws + 12582912);         // [2048][2048] bf16,  8.39 MB
    u16* xb    = (u16*)(ws + 20971520);         // [4096][2048] bf16, 16.78 MB
    u16* qkvb  = (u16*)(ws + 37748736);         // [4096][3072] bf16, 25.17 MB
    u16* vtb   = (u16*)(ws + 62914560);         // [B][512][T]  bf16,  4.19 MB
    u16* yb    = (u16*)(ws + 67108864);         // [4096][2048] bf16, 16.78 MB

    const int M = B_ * T_;

    int n4 = (M * C_) / 4;
    cvt_f32_bf16<<<n4 / 256, 256, 0, stream>>>(x, xb, n4);

    dim3 tb(32, 8);
    xpose_f32_bf16<<<dim3(C_ / 32, C_ / 32), tb, 0, stream>>>(Wq, WqkvT, C_, C_);
    xpose_f32_bf16<<<dim3((NKV_ * HD_) / 32, C_ / 32), tb, 0, stream>>>(Wk, WqkvT + 2048 * 2048, C_, NKV_ * HD_);
    xpose_f32_bf16<<<dim3((NKV_ * HD_) / 32, C_ / 32), tb, 0, stream>>>(Wv, WqkvT + 2560 * 2048, C_, NKV_ * HD_);
    xpose_f32_bf16<<<dim3(C_ / 32, C_ / 32), tb, 0, stream>>>(Wo, WoT, C_, C_);

    // fused QKV projection + in-epilogue RoPE; V pre-transposed into vtb
    // grid = (3072/256)*(4096/256) = 192 workgroups (%8==0 for XCD swizzle)
    gemm_qkv<<<dim3((LDQKV / 256) * (M / 256)), 512, 0, stream>>>(xb, WqkvT, qkvb, vtb, fc, fs, M, LDQKV, C_);

    flash_k<<<dim3(T_ / 128, NH_, B_), 256, 0, stream>>>(qkvb, vtb, yb);

    // grid = (2048/256)*(4096/128) = 256 workgroups = 1/CU (full machine)
    gemm_out<<<dim3((C_ / 256) * (M / 128)), 512, 0, stream>>>(yb, WoT, out, M, C_, C_);
}

// Round 3
// 289.736 us; speedup vs baseline: 1.1111x; 1.0273x over previous
//
#include <hip/hip_runtime.h>

#define B_ 2
#define T_ 2048
#define C_ 2048
#define NH_ 16
#define NKV_ 4
#define HD_ 128
#define REP_ (NH_ / NKV_)
#define LDQKV 3072   // fused qkv row stride (elements)

typedef unsigned short u16;
typedef __bf16 bf16x8v __attribute__((ext_vector_type(8)));
typedef float f32x4v __attribute__((ext_vector_type(4)));

__device__ __forceinline__ u16 f2bf(float f) {
    unsigned int u;
    __builtin_memcpy(&u, &f, 4);
    u += 0x7FFFu + ((u >> 16) & 1u);   // RNE
    return (u16)(u >> 16);
}
__device__ __forceinline__ unsigned int pk2(float a, float b) {
    unsigned int ua, ub;
    __builtin_memcpy(&ua, &a, 4);
    __builtin_memcpy(&ub, &b, 4);
    ua += 0x8000u; ub += 0x8000u;
    return (ua >> 16) | (ub & 0xFFFF0000u);
}
__device__ __forceinline__ bf16x8v load8(const u16* p) {
    return *reinterpret_cast<const bf16x8v*>(p);
}
// async global->LDS, 16B per lane. LDS dest must be wave-uniform base + lane*16B.
__device__ __forceinline__ void gl16(const u16* g, u16* l) {
    __builtin_amdgcn_global_load_lds(
        (const __attribute__((address_space(1))) void*)(g),
        (__attribute__((address_space(3))) void*)(l), 16, 0, 0);
}
// stage one 128-row x 64-col bf16 half-tile: 2 gl16/thread (512 threads)
__device__ __forceinline__ void stg(const u16* g, u16* l, int tid, int K) {
    gl16(g, l + tid * 8);
    gl16(g + (size_t)64 * K, l + 4096 + tid * 8);
}
// stage one 192-row x 64-col bf16 tile: 3 gl16/thread (512 threads)
__device__ __forceinline__ void stgB3(const u16* g, u16* l, int tid, int K) {
    gl16(g, l + tid * 8);
    gl16(g + (size_t)64 * K, l + 4096 + tid * 8);
    gl16(g + (size_t)128 * K, l + 8192 + tid * 8);
}
#define BAR()      __builtin_amdgcn_s_barrier()
#define LGKM0()    asm volatile("s_waitcnt lgkmcnt(0)" ::: "memory")
#define SCHED0()   __builtin_amdgcn_sched_barrier(0)
#define PRIO(x)    __builtin_amdgcn_s_setprio(x)

// ---------------------------------------------------------------------------
// fp32 -> bf16 elementwise convert
// ---------------------------------------------------------------------------
__global__ void cvt_f32_bf16(const float* __restrict__ in, u16* __restrict__ out, int n4) {
    int i = blockIdx.x * blockDim.x + threadIdx.x;
    if (i >= n4) return;
    float4 v = reinterpret_cast<const float4*>(in)[i];
    ushort4 o;
    o.x = f2bf(v.x); o.y = f2bf(v.y); o.z = f2bf(v.z); o.w = f2bf(v.w);
    reinterpret_cast<ushort4*>(out)[i] = o;
}

// ---------------------------------------------------------------------------
// fp32 in [R,Cc] -> bf16 out [Cc,R]; out row stride = R.
// ---------------------------------------------------------------------------
__global__ void xpose_f32_bf16(const float* __restrict__ in, u16* __restrict__ out,
                               int R, int Cc) {
    __shared__ u16 tile[32][33];
    int bx = blockIdx.x * 32, by = blockIdx.y * 32;
    int tx = threadIdx.x, ty = threadIdx.y;  // 32 x 8
    for (int i = 0; i < 32; i += 8)
        tile[ty + i][tx] = f2bf(in[(size_t)(by + ty + i) * Cc + bx + tx]);
    __syncthreads();
    for (int i = 0; i < 32; i += 8)
        out[(size_t)(bx + ty + i) * R + by + tx] = tile[tx][ty + i];
}

// ---------------------------------------------------------------------------
// Fused QKV GEMM: 256x192 tile (grid 16x16 = 256 WGs = full machine), BK=64,
// 512 thr = 8 waves (2M x 4N; per-wave 128x48). 3 phases/K-tile, 16 MFMA each:
//   ph1 mt0-3 x nt0-1: 12 ds_read | stage A-h0(t+1)
//   ph2 mt4-7 x nt0-1: 10 ds_read (incl b2) | stage A-h1(t+1)
//   ph3 all-mt x nt2 (register-only) | stage B(t+2), vmcnt(3)
// vmcnt(3) once/tile validates A0,A1(t+1) (B(t+1) older); 5 barriers/tile.
// Stage-WAR rule: every stage targets a region whose last ds_read was in an
// earlier phase (reads complete at that phase's lgkm0, before its end-bar).
// ---------------------------------------------------------------------------
__global__ __launch_bounds__(512, 2) void gemm_qkv(const u16* __restrict__ A,
                                                   const u16* __restrict__ BT,
                                                   u16* __restrict__ Cq,
                                                   u16* __restrict__ vtb,
                                                   const float* __restrict__ cb,
                                                   const float* __restrict__ sb,
                                                   int M, int N, int K) {
    __shared__ __align__(16) u16 As[2][2][8192];   // [dbuf][row-half][128x64], 64 KB
    __shared__ __align__(16) u16 Bs[2][12288];     // [dbuf][192 rows x 64],   48 KB
    int tid = threadIdx.x;
    int lane = tid & 63, wave = tid >> 6;
    int wm = wave >> 2, wn = wave & 3;              // 2M x 4N wave grid
    int m15 = lane & 15, quad = lane >> 4;

    // bijective XCD swizzle (grid % 8 == 0)
    int nbx = N / 192;                              // 16 col-tiles
    int bid = blockIdx.x, cpx = gridDim.x >> 3;
    int swz = (bid & 7) * cpx + (bid >> 3);
    int m0 = (swz / nbx) * 256, n0 = (swz % nbx) * 192;

    int r_ = tid >> 3, c_ = tid & 7;
    const u16* gA0 = A + (size_t)(m0 + r_) * K + ((c_ ^ (r_ & 7)) * 8);
    const u16* gB0 = BT + (size_t)(n0 + r_) * K + ((c_ ^ (r_ & 7)) * 8);

    int sw8 = m15 & 7;
    int co0 = (quad ^ sw8) * 8;          // kc=0 chunk (swizzled read)
    int co1 = ((4 + quad) ^ sw8) * 8;    // kc=1 chunk
    const u16* aB = &As[0][0][0] + wm * 8192 + m15 * 64;      // + d*16384 + mt*1024
    const u16* bB = &Bs[0][0] + (wn * 48 + m15) * 64;         // + d*12288 + nt*1024

    f32x4v acc[8][3] = {};
    int NT = K >> 6;

    // prologue: B(0) A0(0) A1(0) B(1); vmcnt(3) => tile 0 resident
    stgB3(gB0, &Bs[0][0], tid, K);
    stg(gA0, &As[0][0][0], tid, K);
    stg(gA0 + (size_t)128 * K, &As[0][1][0], tid, K);
    stgB3(gB0 + 64, &Bs[1][0], tid, K);
    asm volatile("s_waitcnt vmcnt(3)" ::: "memory");
    SCHED0();
    BAR();

    for (int t = 0; t < NT; t++) {
        int d = t & 1;
        const u16* aT = aB + d * 16384;
        const u16* bT = bB + d * 12288;
        bf16x8v a0[4][2], a1[4][2], bv[3][2];

        // ---- phase 1: mt0-3 x nt0-1
#pragma unroll
        for (int mt = 0; mt < 4; mt++) {
            a0[mt][0] = load8(aT + mt * 1024 + co0);
            a0[mt][1] = load8(aT + mt * 1024 + co1);
        }
#pragma unroll
        for (int nt = 0; nt < 2; nt++) {
            bv[nt][0] = load8(bT + nt * 1024 + co0);
            bv[nt][1] = load8(bT + nt * 1024 + co1);
        }
        if (t + 1 < NT) stg(gA0 + (t + 1) * 64, &As[1 - d][0][0], tid, K);
        BAR(); LGKM0(); SCHED0(); PRIO(1);
#pragma unroll
        for (int kc = 0; kc < 2; kc++)
#pragma unroll
            for (int mt = 0; mt < 4; mt++)
#pragma unroll
                for (int nt = 0; nt < 2; nt++)
                    acc[mt][nt] = __builtin_amdgcn_mfma_f32_16x16x32_bf16(
                        a0[mt][kc], bv[nt][kc], acc[mt][nt], 0, 0, 0);
        PRIO(0); BAR();

        // ---- phase 2: mt4-7 x nt0-1 (also read b2 for ph3)
#pragma unroll
        for (int mt = 0; mt < 4; mt++) {
            a1[mt][0] = load8(aT + (mt + 4) * 1024 + co0);
            a1[mt][1] = load8(aT + (mt + 4) * 1024 + co1);
        }
        bv[2][0] = load8(bT + 2048 + co0);
        bv[2][1] = load8(bT + 2048 + co1);
        if (t + 1 < NT) stg(gA0 + (size_t)128 * K + (t + 1) * 64, &As[1 - d][1][0], tid, K);
        BAR(); LGKM0(); SCHED0(); PRIO(1);
#pragma unroll
        for (int kc = 0; kc < 2; kc++)
#pragma unroll
            for (int mt = 0; mt < 4; mt++)
#pragma unroll
                for (int nt = 0; nt < 2; nt++)
                    acc[mt + 4][nt] = __builtin_amdgcn_mfma_f32_16x16x32_bf16(
                        a1[mt][kc], bv[nt][kc], acc[mt + 4][nt], 0, 0, 0);
        PRIO(0); BAR();

        // ---- phase 3: all mt x nt2 (register-only; Bs[d] reads all done ph1/ph2)
        if (t + 2 < NT) stgB3(gB0 + (t + 2) * 64, &Bs[d][0], tid, K);
        PRIO(1);
#pragma unroll
        for (int kc = 0; kc < 2; kc++)
#pragma unroll
            for (int mt = 0; mt < 4; mt++)
                acc[mt][2] = __builtin_amdgcn_mfma_f32_16x16x32_bf16(
                    a0[mt][kc], bv[2][kc], acc[mt][2], 0, 0, 0);
#pragma unroll
        for (int kc = 0; kc < 2; kc++)
#pragma unroll
            for (int mt = 0; mt < 4; mt++)
                acc[mt + 4][2] = __builtin_amdgcn_mfma_f32_16x16x32_bf16(
                    a1[mt][kc], bv[2][kc], acc[mt + 4][2], 0, 0, 0);
        PRIO(0);
        if (t + 2 < NT) { asm volatile("s_waitcnt vmcnt(3)" ::: "memory"); }
        else            { asm volatile("s_waitcnt vmcnt(0)" ::: "memory"); }
        SCHED0();
        BAR();
    }

    // epilogue: per-nt branch (Q/K vs V); boundary 2560 is 16-aligned so each
    // 16-col block is uniform; RoPE partner col c^1 lives at lane m15^1.
#pragma unroll
    for (int mt = 0; mt < 8; mt++)
#pragma unroll
        for (int nt = 0; nt < 3; nt++) {
            int c = n0 + wn * 48 + nt * 16 + m15;
            if (c >= 2560) {
                int hd = c - 2560;
                int mbase = m0 + wm * 128 + mt * 16 + quad * 4;
                int bb = mbase >> 11, tok = mbase & 2047;
                int g = (tok & 31) >> 2;
                int off = (tok & ~31) + ((g & 3) * 8 + (g >> 2) * 4);
                ushort4 pk;
                pk.x = f2bf(acc[mt][nt][0]);
                pk.y = f2bf(acc[mt][nt][1]);
                pk.z = f2bf(acc[mt][nt][2]);
                pk.w = f2bf(acc[mt][nt][3]);
                *reinterpret_cast<ushort4*>(vtb + ((size_t)bb * 512 + hd) * T_ + off) = pk;
            } else {
                int i = (c & 127) >> 1;
                float sgn = (c & 1) ? 1.f : -1.f;
#pragma unroll
                for (int r = 0; r < 4; r++) {
                    int mrow = m0 + wm * 128 + mt * 16 + quad * 4 + r;
                    int tok = mrow & 2047;
                    float cv = cb[tok * 64 + i];
                    float sv = sb[tok * 64 + i];
                    float v = acc[mt][nt][r];
                    float pval = __shfl_xor(v, 1, 64);
                    float outv = fmaf(v, cv, pval * sv * sgn);
                    Cq[(size_t)mrow * N + c] = f2bf(outv);
                }
            }
        }
}

// ---------------------------------------------------------------------------
// Out-proj GEMM (fp32 out): 128x256 tile (grid 256 WGs), 4-phase pipeline.
// (unchanged from round 2 — control kernel)
// ---------------------------------------------------------------------------
__global__ __launch_bounds__(512, 2) void gemm_out(const u16* __restrict__ A,
                                                   const u16* __restrict__ BT,
                                                   float* __restrict__ C,
                                                   int M, int N, int K) {
    __shared__ __align__(16) u16 As2[2][8192];      // [dbuf][128 rows x 64]
    __shared__ __align__(16) u16 Bs2[2][2][8192];   // [dbuf][col-half][128 x 64]
    int tid = threadIdx.x;
    int lane = tid & 63, wave = tid >> 6;
    int wm = wave >> 2, wn = wave & 3;              // per-wave 64 rows x 64 cols
    int m15 = lane & 15, quad = lane >> 4;

    int nbx = N >> 8;                               // = 8
    int bid = blockIdx.x, cpx = gridDim.x >> 3;
    int swz = (bid & 7) * cpx + (bid >> 3);
    int m0 = (swz / nbx) * 128, n0 = (swz % nbx) * 256;

    const u16* gA0 = A + (size_t)(m0 + (tid >> 3)) * K + (((tid & 7) ^ ((tid >> 3) & 7)) * 8);
    const u16* gB0 = BT + (size_t)(n0 + (tid >> 3)) * K + (((tid & 7) ^ ((tid >> 3) & 7)) * 8);

    int sw8 = m15 & 7;
    int co0 = (quad ^ sw8) * 8;
    int co1 = ((4 + quad) ^ sw8) * 8;
    const u16* aB = &As2[0][0] + (wm * 64 + m15) * 64;
    const u16* bB = &Bs2[0][0][0] + (wn >> 1) * 8192 + ((wn & 1) * 64 + m15) * 64;

    f32x4v acc[4][4] = {};
    int NT = K >> 6;

    stg(gB0, &Bs2[0][0][0], tid, K);
    stg(gB0 + (size_t)128 * K, &Bs2[0][1][0], tid, K);
    stg(gA0, &As2[0][0], tid, K);
    stg(gB0 + 64, &Bs2[1][0][0], tid, K);
    stg(gB0 + (size_t)128 * K + 64, &Bs2[1][1][0], tid, K);
    asm volatile("s_waitcnt vmcnt(4)" ::: "memory");
    SCHED0();
    BAR();

    for (int t = 0; t < NT; t++) {
        int d = t & 1;
        const u16* aT = aB + d * 8192;
        const u16* bT = bB + d * 16384;
        bf16x8v a0[2][2], a1[2][2], b0[2][2], b1[2][2];

        // ---- phase 1
#pragma unroll
        for (int mt = 0; mt < 2; mt++) {
            a0[mt][0] = load8(aT + mt * 1024 + co0);
            a0[mt][1] = load8(aT + mt * 1024 + co1);
        }
#pragma unroll
        for (int nt = 0; nt < 2; nt++) {
            b0[nt][0] = load8(bT + nt * 1024 + co0);
            b0[nt][1] = load8(bT + nt * 1024 + co1);
        }
        if (t + 1 < NT) stg(gA0 + (t + 1) * 64, &As2[1 - d][0], tid, K);
        BAR(); LGKM0(); SCHED0(); PRIO(1);
#pragma unroll
        for (int kc = 0; kc < 2; kc++)
#pragma unroll
            for (int mt = 0; mt < 2; mt++)
#pragma unroll
                for (int nt = 0; nt < 2; nt++)
                    acc[mt][nt] = __builtin_amdgcn_mfma_f32_16x16x32_bf16(
                        a0[mt][kc], b0[nt][kc], acc[mt][nt], 0, 0, 0);
        PRIO(0); BAR();

        // ---- phase 2
#pragma unroll
        for (int nt = 0; nt < 2; nt++) {
            b1[nt][0] = load8(bT + (nt + 2) * 1024 + co0);
            b1[nt][1] = load8(bT + (nt + 2) * 1024 + co1);
        }
        BAR(); LGKM0(); SCHED0(); PRIO(1);
#pragma unroll
        for (int kc = 0; kc < 2; kc++)
#pragma unroll
            for (int mt = 0; mt < 2; mt++)
#pragma unroll
                for (int nt = 0; nt < 2; nt++)
                    acc[mt][nt + 2] = __builtin_amdgcn_mfma_f32_16x16x32_bf16(
                        a0[mt][kc], b1[nt][kc], acc[mt][nt + 2], 0, 0, 0);
        PRIO(0); BAR();

        // ---- phase 3
#pragma unroll
        for (int mt = 0; mt < 2; mt++) {
            a1[mt][0] = load8(aT + (mt + 2) * 1024 + co0);
            a1[mt][1] = load8(aT + (mt + 2) * 1024 + co1);
        }
        if (t + 2 < NT) stg(gB0 + (t + 2) * 64, &Bs2[d][0][0], tid, K);
        BAR(); LGKM0(); SCHED0(); PRIO(1);
#pragma unroll
        for (int kc = 0; kc < 2; kc++)
#pragma unroll
            for (int mt = 0; mt < 2; mt++)
#pragma unroll
                for (int nt = 0; nt < 2; nt++)
                    acc[mt + 2][nt] = __builtin_amdgcn_mfma_f32_16x16x32_bf16(
                        a1[mt][kc], b0[nt][kc], acc[mt + 2][nt], 0, 0, 0);
        PRIO(0); BAR();

        // ---- phase 4
        if (t + 2 < NT) stg(gB0 + (size_t)128 * K + (t + 2) * 64, &Bs2[d][1][0], tid, K);
        BAR(); PRIO(1);
#pragma unroll
        for (int kc = 0; kc < 2; kc++)
#pragma unroll
            for (int mt = 0; mt < 2; mt++)
#pragma unroll
                for (int nt = 0; nt < 2; nt++)
                    acc[mt + 2][nt + 2] = __builtin_amdgcn_mfma_f32_16x16x32_bf16(
                        a1[mt][kc], b1[nt][kc], acc[mt + 2][nt + 2], 0, 0, 0);
        PRIO(0);
        if (t + 2 < NT) { asm volatile("s_waitcnt vmcnt(4)" ::: "memory"); }
        else            { asm volatile("s_waitcnt vmcnt(0)" ::: "memory"); }
        SCHED0();
        BAR();
    }

#pragma unroll
    for (int mt = 0; mt < 4; mt++)
#pragma unroll
        for (int nt = 0; nt < 4; nt++) {
            int c = n0 + wn * 64 + nt * 16 + m15;
#pragma unroll
            for (int r = 0; r < 4; r++) {
                int mrow = m0 + wm * 64 + mt * 16 + quad * 4 + r;
                C[(size_t)mrow * N + c] = acc[mt][nt][r];
            }
        }
}

// ---------------------------------------------------------------------------
// Flash attention v5: S^T orientation, fixed-max softmax, KVBLK=64 with
// double-buffered K/V (LDS 64 KB -> 2 blocks/CU) and counted-vmcnt pipeline:
// per iter {16 ds_read K || stage K(t+1) | bar | lgkm0 | QK MFMA | vmcnt(4) | bar}
//          {softmax+pack || 16 ds_read V || stage V(t+1) | bar | lgkm0 | PV MFMA | vmcnt(4) | bar}
// Each staged buffer is waited one full phase after issue; never vmcnt(0)
// mid-loop. Stage targets buffers whose last ds_read was 2 barriers earlier.
// ---------------------------------------------------------------------------
__device__ __forceinline__ void stgK64(const u16* kB, u16* Kl, int kt, int tid) {
    int keyc = tid >> 4, ch = tid & 15;
    const u16* g = kB + (size_t)(kt + keyc) * LDQKV + (ch ^ keyc) * 8;
    u16* l = Kl + tid * 8;
#pragma unroll
    for (int j = 0; j < 4; j++) {
        gl16(g, l);
        g += (size_t)16 * LDQKV;
        l += 2048;
    }
}
__device__ __forceinline__ void stgV64(const u16* vB, u16* Vl, int kt, int tid) {
    int hdc = tid >> 3, ch = tid & 7;
    const u16* g = vB + (size_t)hdc * T_ + kt + (ch ^ (hdc & 7)) * 8;
    u16* l = Vl + tid * 8;
#pragma unroll
    for (int j = 0; j < 4; j++) {
        gl16(g, l);
        g += (size_t)32 * T_;
        l += 2048;
    }
}

__global__ __launch_bounds__(256) void flash_k(const u16* __restrict__ qkv,
                                               const u16* __restrict__ vtb,
                                               u16* __restrict__ yb) {
    __shared__ __align__(16) u16 Kl[2][64 * 128];   // 32 KB
    __shared__ __align__(16) u16 Vl[2][128 * 64];   // 32 KB -> 64 KB total: 2 blocks/CU
    int h = blockIdx.y, b = blockIdx.z;
    int kv = h / REP_;
    int tid = threadIdx.x;
    int lane = tid & 63, wave = tid >> 6;
    int m15 = lane & 15, quad = lane >> 4;
    int sw8 = m15 & 7;
    const u16* kB = qkv + (size_t)b * T_ * LDQKV + 2048 + kv * HD_;
    const u16* vB = vtb + ((size_t)(b * NKV_ + kv)) * HD_ * T_;
    const float scale2 = 0.1275173723f;  // 1/sqrt(128) * log2(e)
    const float M0b = 8.0f;              // fixed max (exp2 domain)
    const float NEG = -3.0e38f;

    for (int p = 0; p < 2; p++) {
        int qt = (p == 0) ? (int)blockIdx.x : (31 - (int)blockIdx.x);
        int qt0 = qt * 64;
        int q_i = qt0 + wave * 16 + m15;     // this lane's query (col of S^T)
        const u16* qp = qkv + (size_t)(b * T_ + q_i) * LDQKV + h * HD_ + quad * 8;
        bf16x8v qf[4];
#pragma unroll
        for (int kc = 0; kc < 4; kc++) qf[kc] = load8(qp + kc * 32);
        f32x4v o[8] = {};
        f32x4v lacc = {};
        int NT = qt + 1;

        // prologue: K0 V0 K1 V1; vmcnt(8) => tile0 resident (also drains prior
        // pass's epilogue stores and qf loads, which are older)
        stgK64(kB, &Kl[0][0], 0, tid);
        stgV64(vB, &Vl[0][0], 0, tid);
        stgK64(kB, &Kl[1][0], 64, tid);
        stgV64(vB, &Vl[1][0], 64, tid);
        asm volatile("s_waitcnt vmcnt(8)" ::: "memory");
        SCHED0();
        BAR();

        for (int it = 0; it < NT; it++) {
            int cur = it & 1;
            int kt = it * 64;
            const u16* Kc = &Kl[cur][0];
            const u16* Vc = &Vl[cur][0];

            // ---- phase A: QK^T on 64 keys
            bf16x8v kf[4][4];
#pragma unroll
            for (int nt = 0; nt < 4; nt++) {
                const u16* kls = Kc + (nt * 16 + m15) * 128;
#pragma unroll
                for (int kc = 0; kc < 4; kc++)
                    kf[nt][kc] = load8(kls + (((kc * 4 + quad) ^ m15) * 8));
            }
            if (it >= 1 && it + 1 < NT) stgK64(kB, &Kl[1 - cur][0], kt + 64, tid);
            BAR(); LGKM0(); SCHED0(); PRIO(1);
            f32x4v s4[4] = {};
#pragma unroll
            for (int nt = 0; nt < 4; nt++)
#pragma unroll
                for (int kc = 0; kc < 4; kc++)
                    s4[nt] = __builtin_amdgcn_mfma_f32_16x16x32_bf16(
                        kf[nt][kc], qf[kc], s4[nt], 0, 0, 0);
            PRIO(0);
            if (it + 1 < NT) { asm volatile("s_waitcnt vmcnt(4)" ::: "memory"); }
            else             { asm volatile("s_waitcnt vmcnt(0)" ::: "memory"); }
            SCHED0(); BAR();

            // ---- phase B: softmax + PV
            if (kt + 64 > qt0) {                 // causal mask (last iter only)
#pragma unroll
                for (int nt = 0; nt < 4; nt++) {
                    int key = kt + nt * 16 + quad * 4;
#pragma unroll
                    for (int r = 0; r < 4; r++)
                        if (key + r > q_i) s4[nt][r] = NEG;
                }
            }
#pragma unroll
            for (int nt = 0; nt < 4; nt++) {
#pragma unroll
                for (int r = 0; r < 4; r++)
                    s4[nt][r] = exp2f(fmaf(s4[nt][r], scale2, -M0b));
                lacc += s4[nt];
            }
            bf16x8v pf[2];
#pragma unroll
            for (int c = 0; c < 2; c++) {
                unsigned int w[4];
                w[0] = pk2(s4[2 * c][0], s4[2 * c][1]);
                w[1] = pk2(s4[2 * c][2], s4[2 * c][3]);
                w[2] = pk2(s4[2 * c + 1][0], s4[2 * c + 1][1]);
                w[3] = pk2(s4[2 * c + 1][2], s4[2 * c + 1][3]);
                __builtin_memcpy(&pf[c], w, 16);
            }
            bf16x8v vf[2][8];
#pragma unroll
            for (int c = 0; c < 2; c++)
#pragma unroll
                for (int dt = 0; dt < 8; dt++)
                    vf[c][dt] = load8(Vc + (dt * 16 + m15) * 64 + (((c * 4 + quad) ^ sw8) * 8));
            if (it >= 1 && it + 1 < NT) stgV64(vB, &Vl[1 - cur][0], kt + 64, tid);
            BAR(); LGKM0(); SCHED0(); PRIO(1);
#pragma unroll
            for (int c = 0; c < 2; c++)
#pragma unroll
                for (int dt = 0; dt < 8; dt++)
                    o[dt] = __builtin_amdgcn_mfma_f32_16x16x32_bf16(
                        vf[c][dt], pf[c], o[dt], 0, 0, 0);
            PRIO(0);
            if (it + 1 < NT) { asm volatile("s_waitcnt vmcnt(4)" ::: "memory"); }
            SCHED0(); BAR();
        }

        // epilogue: l = sum of this lane's 4 partials, then across quads
        float l = lacc[0] + lacc[1] + lacc[2] + lacc[3];
        l += __shfl_xor(l, 16, 64);
        l += __shfl_xor(l, 32, 64);
        float inv = 1.f / l;
        u16* yp = yb + (size_t)(b * T_ + q_i) * C_ + h * HD_ + quad * 4;
#pragma unroll
        for (int dt = 0; dt < 8; dt++) {
            ushort4 pk;
            pk.x = f2bf(o[dt][0] * inv);
            pk.y = f2bf(o[dt][1] * inv);
            pk.z = f2bf(o[dt][2] * inv);
            pk.w = f2bf(o[dt][3] * inv);
            *reinterpret_cast<ushort4*>(yp + dt * 16) = pk;
        }
    }
}

// ---------------------------------------------------------------------------
extern "C" void kernel_launch(void* const* d_in, const int* in_sizes, int n_in,
                              void* d_out, int out_size, void* d_ws, size_t ws_size,
                              hipStream_t stream) {
    const float* x  = (const float*)d_in[0];
    const float* Wq = (const float*)d_in[1];
    const float* Wk = (const float*)d_in[2];
    const float* Wv = (const float*)d_in[3];
    const float* Wo = (const float*)d_in[4];
    const float* fc = (const float*)d_in[5];
    const float* fs = (const float*)d_in[6];
    float* out = (float*)d_out;

    char* ws = (char*)d_ws;
    u16* WqkvT = (u16*)(ws);                    // [3072][2048] bf16, 12.58 MB
    u16* WoT   = (u16*)(ws + 12582912);         // [2048][2048] bf16,  8.39 MB
    u16* xb    = (u16*)(ws + 20971520);         // [4096][2048] bf16, 16.78 MB
    u16* qkvb  = (u16*)(ws + 37748736);         // [4096][3072] bf16, 25.17 MB
    u16* vtb   = (u16*)(ws + 62914560);         // [B][512][T]  bf16,  4.19 MB
    u16* yb    = (u16*)(ws + 67108864);         // [4096][2048] bf16, 16.78 MB

    const int M = B_ * T_;

    int n4 = (M * C_) / 4;
    cvt_f32_bf16<<<n4 / 256, 256, 0, stream>>>(x, xb, n4);

    dim3 tb(32, 8);
    xpose_f32_bf16<<<dim3(C_ / 32, C_ / 32), tb, 0, stream>>>(Wq, WqkvT, C_, C_);
    xpose_f32_bf16<<<dim3((NKV_ * HD_) / 32, C_ / 32), tb, 0, stream>>>(Wk, WqkvT + 2048 * 2048, C_, NKV_ * HD_);
    xpose_f32_bf16<<<dim3((NKV_ * HD_) / 32, C_ / 32), tb, 0, stream>>>(Wv, WqkvT + 2560 * 2048, C_, NKV_ * HD_);
    xpose_f32_bf16<<<dim3(C_ / 32, C_ / 32), tb, 0, stream>>>(Wo, WoT, C_, C_);

    // fused QKV projection + in-epilogue RoPE; V pre-transposed into vtb
    // grid = (3072/192)*(4096/256) = 256 workgroups = full machine
    gemm_qkv<<<dim3((LDQKV / 192) * (M / 256)), 512, 0, stream>>>(xb, WqkvT, qkvb, vtb, fc, fs, M, LDQKV, C_);

    flash_k<<<dim3(T_ / 128, NH_, B_), 256, 0, stream>>>(qkvb, vtb, yb);

    // grid = (2048/256)*(4096/128) = 256 workgroups = full machine
    gemm_out<<<dim3((C_ / 256) * (M / 128)), 512, 0, stream>>>(yb, WoT, out, M, C_, C_);
}

// Round 4
// 288.577 us; speedup vs baseline: 1.1156x; 1.0040x over previous
//
#include <hip/hip_runtime.h>

#define B_ 2
#define T_ 2048
#define C_ 2048
#define NH_ 16
#define NKV_ 4
#define HD_ 128
#define REP_ (NH_ / NKV_)
#define LDQKV 3072   // fused qkv row stride (elements)

typedef unsigned short u16;
typedef __bf16 bf16x8v __attribute__((ext_vector_type(8)));
typedef float f32x4v __attribute__((ext_vector_type(4)));

__device__ __forceinline__ u16 f2bf(float f) {
    unsigned int u;
    __builtin_memcpy(&u, &f, 4);
    u += 0x7FFFu + ((u >> 16) & 1u);   // RNE
    return (u16)(u >> 16);
}
// pack two fp32 -> two bf16 in one instr (lo=a, hi=b)
__device__ __forceinline__ unsigned int cvtpk(float a, float b) {
    unsigned int r;
    asm("v_cvt_pk_bf16_f32 %0, %1, %2" : "=v"(r) : "v"(a), "v"(b));
    return r;
}
__device__ __forceinline__ bf16x8v load8(const u16* p) {
    return *reinterpret_cast<const bf16x8v*>(p);
}
// async global->LDS, 16B per lane. LDS dest must be wave-uniform base + lane*16B.
__device__ __forceinline__ void gl16(const u16* g, u16* l) {
    __builtin_amdgcn_global_load_lds(
        (const __attribute__((address_space(1))) void*)(g),
        (__attribute__((address_space(3))) void*)(l), 16, 0, 0);
}
// stage one 128-row x 64-col bf16 half-tile: 2 gl16/thread (512 threads)
__device__ __forceinline__ void stg(const u16* g, u16* l, int tid, int K) {
    gl16(g, l + tid * 8);
    gl16(g + (size_t)64 * K, l + 4096 + tid * 8);
}
// stage one 192-row x 64-col bf16 tile: 3 gl16/thread (512 threads)
__device__ __forceinline__ void stgB3(const u16* g, u16* l, int tid, int K) {
    gl16(g, l + tid * 8);
    gl16(g + (size_t)64 * K, l + 4096 + tid * 8);
    gl16(g + (size_t)128 * K, l + 8192 + tid * 8);
}
#define BAR()      __builtin_amdgcn_s_barrier()
#define LGKM0()    asm volatile("s_waitcnt lgkmcnt(0)" ::: "memory")
#define SCHED0()   __builtin_amdgcn_sched_barrier(0)
#define PRIO(x)    __builtin_amdgcn_s_setprio(x)

// ---------------------------------------------------------------------------
// fp32 -> bf16 elementwise convert
// ---------------------------------------------------------------------------
__global__ void cvt_f32_bf16(const float* __restrict__ in, u16* __restrict__ out, int n4) {
    int i = blockIdx.x * blockDim.x + threadIdx.x;
    if (i >= n4) return;
    float4 v = reinterpret_cast<const float4*>(in)[i];
    ushort4 o;
    o.x = f2bf(v.x); o.y = f2bf(v.y); o.z = f2bf(v.z); o.w = f2bf(v.w);
    reinterpret_cast<ushort4*>(out)[i] = o;
}

// ---------------------------------------------------------------------------
// fp32 in [R,Cc] -> bf16 out [Cc,R]; out row stride = R.
// ---------------------------------------------------------------------------
__global__ void xpose_f32_bf16(const float* __restrict__ in, u16* __restrict__ out,
                               int R, int Cc) {
    __shared__ u16 tile[32][33];
    int bx = blockIdx.x * 32, by = blockIdx.y * 32;
    int tx = threadIdx.x, ty = threadIdx.y;  // 32 x 8
    for (int i = 0; i < 32; i += 8)
        tile[ty + i][tx] = f2bf(in[(size_t)(by + ty + i) * Cc + bx + tx]);
    __syncthreads();
    for (int i = 0; i < 32; i += 8)
        out[(size_t)(bx + ty + i) * R + by + tx] = tile[tx][ty + i];
}

// ---------------------------------------------------------------------------
// Fused QKV GEMM: 256x192 tile (grid 16x16 = 256 WGs = full machine), BK=64,
// 512 thr = 8 waves (2M x 4N; per-wave 128x48). 3 phases/K-tile, 16 MFMA each.
// (unchanged from round 3)
// ---------------------------------------------------------------------------
__global__ __launch_bounds__(512, 2) void gemm_qkv(const u16* __restrict__ A,
                                                   const u16* __restrict__ BT,
                                                   u16* __restrict__ Cq,
                                                   u16* __restrict__ vtb,
                                                   const float* __restrict__ cb,
                                                   const float* __restrict__ sb,
                                                   int M, int N, int K) {
    __shared__ __align__(16) u16 As[2][2][8192];   // [dbuf][row-half][128x64], 64 KB
    __shared__ __align__(16) u16 Bs[2][12288];     // [dbuf][192 rows x 64],   48 KB
    int tid = threadIdx.x;
    int lane = tid & 63, wave = tid >> 6;
    int wm = wave >> 2, wn = wave & 3;              // 2M x 4N wave grid
    int m15 = lane & 15, quad = lane >> 4;

    // bijective XCD swizzle (grid % 8 == 0)
    int nbx = N / 192;                              // 16 col-tiles
    int bid = blockIdx.x, cpx = gridDim.x >> 3;
    int swz = (bid & 7) * cpx + (bid >> 3);
    int m0 = (swz / nbx) * 256, n0 = (swz % nbx) * 192;

    int r_ = tid >> 3, c_ = tid & 7;
    const u16* gA0 = A + (size_t)(m0 + r_) * K + ((c_ ^ (r_ & 7)) * 8);
    const u16* gB0 = BT + (size_t)(n0 + r_) * K + ((c_ ^ (r_ & 7)) * 8);

    int sw8 = m15 & 7;
    int co0 = (quad ^ sw8) * 8;          // kc=0 chunk (swizzled read)
    int co1 = ((4 + quad) ^ sw8) * 8;    // kc=1 chunk
    const u16* aB = &As[0][0][0] + wm * 8192 + m15 * 64;      // + d*16384 + mt*1024
    const u16* bB = &Bs[0][0] + (wn * 48 + m15) * 64;         // + d*12288 + nt*1024

    f32x4v acc[8][3] = {};
    int NT = K >> 6;

    // prologue: B(0) A0(0) A1(0) B(1); vmcnt(3) => tile 0 resident
    stgB3(gB0, &Bs[0][0], tid, K);
    stg(gA0, &As[0][0][0], tid, K);
    stg(gA0 + (size_t)128 * K, &As[0][1][0], tid, K);
    stgB3(gB0 + 64, &Bs[1][0], tid, K);
    asm volatile("s_waitcnt vmcnt(3)" ::: "memory");
    SCHED0();
    BAR();

    for (int t = 0; t < NT; t++) {
        int d = t & 1;
        const u16* aT = aB + d * 16384;
        const u16* bT = bB + d * 12288;
        bf16x8v a0[4][2], a1[4][2], bv[3][2];

        // ---- phase 1: mt0-3 x nt0-1
#pragma unroll
        for (int mt = 0; mt < 4; mt++) {
            a0[mt][0] = load8(aT + mt * 1024 + co0);
            a0[mt][1] = load8(aT + mt * 1024 + co1);
        }
#pragma unroll
        for (int nt = 0; nt < 2; nt++) {
            bv[nt][0] = load8(bT + nt * 1024 + co0);
            bv[nt][1] = load8(bT + nt * 1024 + co1);
        }
        if (t + 1 < NT) stg(gA0 + (t + 1) * 64, &As[1 - d][0][0], tid, K);
        BAR(); LGKM0(); SCHED0(); PRIO(1);
#pragma unroll
        for (int kc = 0; kc < 2; kc++)
#pragma unroll
            for (int mt = 0; mt < 4; mt++)
#pragma unroll
                for (int nt = 0; nt < 2; nt++)
                    acc[mt][nt] = __builtin_amdgcn_mfma_f32_16x16x32_bf16(
                        a0[mt][kc], bv[nt][kc], acc[mt][nt], 0, 0, 0);
        PRIO(0); BAR();

        // ---- phase 2: mt4-7 x nt0-1 (also read b2 for ph3)
#pragma unroll
        for (int mt = 0; mt < 4; mt++) {
            a1[mt][0] = load8(aT + (mt + 4) * 1024 + co0);
            a1[mt][1] = load8(aT + (mt + 4) * 1024 + co1);
        }
        bv[2][0] = load8(bT + 2048 + co0);
        bv[2][1] = load8(bT + 2048 + co1);
        if (t + 1 < NT) stg(gA0 + (size_t)128 * K + (t + 1) * 64, &As[1 - d][1][0], tid, K);
        BAR(); LGKM0(); SCHED0(); PRIO(1);
#pragma unroll
        for (int kc = 0; kc < 2; kc++)
#pragma unroll
            for (int mt = 0; mt < 4; mt++)
#pragma unroll
                for (int nt = 0; nt < 2; nt++)
                    acc[mt + 4][nt] = __builtin_amdgcn_mfma_f32_16x16x32_bf16(
                        a1[mt][kc], bv[nt][kc], acc[mt + 4][nt], 0, 0, 0);
        PRIO(0); BAR();

        // ---- phase 3: all mt x nt2 (register-only; Bs[d] reads all done ph1/ph2)
        if (t + 2 < NT) stgB3(gB0 + (t + 2) * 64, &Bs[d][0], tid, K);
        PRIO(1);
#pragma unroll
        for (int kc = 0; kc < 2; kc++)
#pragma unroll
            for (int mt = 0; mt < 4; mt++)
                acc[mt][2] = __builtin_amdgcn_mfma_f32_16x16x32_bf16(
                    a0[mt][kc], bv[2][kc], acc[mt][2], 0, 0, 0);
#pragma unroll
        for (int kc = 0; kc < 2; kc++)
#pragma unroll
            for (int mt = 0; mt < 4; mt++)
                acc[mt + 4][2] = __builtin_amdgcn_mfma_f32_16x16x32_bf16(
                    a1[mt][kc], bv[2][kc], acc[mt + 4][2], 0, 0, 0);
        PRIO(0);
        if (t + 2 < NT) { asm volatile("s_waitcnt vmcnt(3)" ::: "memory"); }
        else            { asm volatile("s_waitcnt vmcnt(0)" ::: "memory"); }
        SCHED0();
        BAR();
    }

    // epilogue: per-nt branch (Q/K vs V); boundary 2560 is 16-aligned so each
    // 16-col block is uniform; RoPE partner col c^1 lives at lane m15^1.
#pragma unroll
    for (int mt = 0; mt < 8; mt++)
#pragma unroll
        for (int nt = 0; nt < 3; nt++) {
            int c = n0 + wn * 48 + nt * 16 + m15;
            if (c >= 2560) {
                int hd = c - 2560;
                int mbase = m0 + wm * 128 + mt * 16 + quad * 4;
                int bb = mbase >> 11, tok = mbase & 2047;
                int g = (tok & 31) >> 2;
                int off = (tok & ~31) + ((g & 3) * 8 + (g >> 2) * 4);
                ushort4 pk;
                pk.x = f2bf(acc[mt][nt][0]);
                pk.y = f2bf(acc[mt][nt][1]);
                pk.z = f2bf(acc[mt][nt][2]);
                pk.w = f2bf(acc[mt][nt][3]);
                *reinterpret_cast<ushort4*>(vtb + ((size_t)bb * 512 + hd) * T_ + off) = pk;
            } else {
                int i = (c & 127) >> 1;
                float sgn = (c & 1) ? 1.f : -1.f;
#pragma unroll
                for (int r = 0; r < 4; r++) {
                    int mrow = m0 + wm * 128 + mt * 16 + quad * 4 + r;
                    int tok = mrow & 2047;
                    float cv = cb[tok * 64 + i];
                    float sv = sb[tok * 64 + i];
                    float v = acc[mt][nt][r];
                    float pval = __shfl_xor(v, 1, 64);
                    float outv = fmaf(v, cv, pval * sv * sgn);
                    Cq[(size_t)mrow * N + c] = f2bf(outv);
                }
            }
        }
}

// ---------------------------------------------------------------------------
// Out-proj GEMM (fp32 out): 128x256 tile (grid 256 WGs), 4-phase pipeline.
// (unchanged — control kernel)
// ---------------------------------------------------------------------------
__global__ __launch_bounds__(512, 2) void gemm_out(const u16* __restrict__ A,
                                                   const u16* __restrict__ BT,
                                                   float* __restrict__ C,
                                                   int M, int N, int K) {
    __shared__ __align__(16) u16 As2[2][8192];      // [dbuf][128 rows x 64]
    __shared__ __align__(16) u16 Bs2[2][2][8192];   // [dbuf][col-half][128 x 64]
    int tid = threadIdx.x;
    int lane = tid & 63, wave = tid >> 6;
    int wm = wave >> 2, wn = wave & 3;              // per-wave 64 rows x 64 cols
    int m15 = lane & 15, quad = lane >> 4;

    int nbx = N >> 8;                               // = 8
    int bid = blockIdx.x, cpx = gridDim.x >> 3;
    int swz = (bid & 7) * cpx + (bid >> 3);
    int m0 = (swz / nbx) * 128, n0 = (swz % nbx) * 256;

    const u16* gA0 = A + (size_t)(m0 + (tid >> 3)) * K + (((tid & 7) ^ ((tid >> 3) & 7)) * 8);
    const u16* gB0 = BT + (size_t)(n0 + (tid >> 3)) * K + (((tid & 7) ^ ((tid >> 3) & 7)) * 8);

    int sw8 = m15 & 7;
    int co0 = (quad ^ sw8) * 8;
    int co1 = ((4 + quad) ^ sw8) * 8;
    const u16* aB = &As2[0][0] + (wm * 64 + m15) * 64;
    const u16* bB = &Bs2[0][0][0] + (wn >> 1) * 8192 + ((wn & 1) * 64 + m15) * 64;

    f32x4v acc[4][4] = {};
    int NT = K >> 6;

    stg(gB0, &Bs2[0][0][0], tid, K);
    stg(gB0 + (size_t)128 * K, &Bs2[0][1][0], tid, K);
    stg(gA0, &As2[0][0], tid, K);
    stg(gB0 + 64, &Bs2[1][0][0], tid, K);
    stg(gB0 + (size_t)128 * K + 64, &Bs2[1][1][0], tid, K);
    asm volatile("s_waitcnt vmcnt(4)" ::: "memory");
    SCHED0();
    BAR();

    for (int t = 0; t < NT; t++) {
        int d = t & 1;
        const u16* aT = aB + d * 8192;
        const u16* bT = bB + d * 16384;
        bf16x8v a0[2][2], a1[2][2], b0[2][2], b1[2][2];

        // ---- phase 1
#pragma unroll
        for (int mt = 0; mt < 2; mt++) {
            a0[mt][0] = load8(aT + mt * 1024 + co0);
            a0[mt][1] = load8(aT + mt * 1024 + co1);
        }
#pragma unroll
        for (int nt = 0; nt < 2; nt++) {
            b0[nt][0] = load8(bT + nt * 1024 + co0);
            b0[nt][1] = load8(bT + nt * 1024 + co1);
        }
        if (t + 1 < NT) stg(gA0 + (t + 1) * 64, &As2[1 - d][0], tid, K);
        BAR(); LGKM0(); SCHED0(); PRIO(1);
#pragma unroll
        for (int kc = 0; kc < 2; kc++)
#pragma unroll
            for (int mt = 0; mt < 2; mt++)
#pragma unroll
                for (int nt = 0; nt < 2; nt++)
                    acc[mt][nt] = __builtin_amdgcn_mfma_f32_16x16x32_bf16(
                        a0[mt][kc], b0[nt][kc], acc[mt][nt], 0, 0, 0);
        PRIO(0); BAR();

        // ---- phase 2
#pragma unroll
        for (int nt = 0; nt < 2; nt++) {
            b1[nt][0] = load8(bT + (nt + 2) * 1024 + co0);
            b1[nt][1] = load8(bT + (nt + 2) * 1024 + co1);
        }
        BAR(); LGKM0(); SCHED0(); PRIO(1);
#pragma unroll
        for (int kc = 0; kc < 2; kc++)
#pragma unroll
            for (int mt = 0; mt < 2; mt++)
#pragma unroll
                for (int nt = 0; nt < 2; nt++)
                    acc[mt][nt + 2] = __builtin_amdgcn_mfma_f32_16x16x32_bf16(
                        a0[mt][kc], b1[nt][kc], acc[mt][nt + 2], 0, 0, 0);
        PRIO(0); BAR();

        // ---- phase 3
#pragma unroll
        for (int mt = 0; mt < 2; mt++) {
            a1[mt][0] = load8(aT + (mt + 2) * 1024 + co0);
            a1[mt][1] = load8(aT + (mt + 2) * 1024 + co1);
        }
        if (t + 2 < NT) stg(gB0 + (t + 2) * 64, &Bs2[d][0][0], tid, K);
        BAR(); LGKM0(); SCHED0(); PRIO(1);
#pragma unroll
        for (int kc = 0; kc < 2; kc++)
#pragma unroll
            for (int mt = 0; mt < 2; mt++)
#pragma unroll
                for (int nt = 0; nt < 2; nt++)
                    acc[mt + 2][nt] = __builtin_amdgcn_mfma_f32_16x16x32_bf16(
                        a1[mt][kc], b0[nt][kc], acc[mt + 2][nt], 0, 0, 0);
        PRIO(0); BAR();

        // ---- phase 4
        if (t + 2 < NT) stg(gB0 + (size_t)128 * K + (t + 2) * 64, &Bs2[d][1][0], tid, K);
        BAR(); PRIO(1);
#pragma unroll
        for (int kc = 0; kc < 2; kc++)
#pragma unroll
            for (int mt = 0; mt < 2; mt++)
#pragma unroll
                for (int nt = 0; nt < 2; nt++)
                    acc[mt + 2][nt + 2] = __builtin_amdgcn_mfma_f32_16x16x32_bf16(
                        a1[mt][kc], b1[nt][kc], acc[mt + 2][nt + 2], 0, 0, 0);
        PRIO(0);
        if (t + 2 < NT) { asm volatile("s_waitcnt vmcnt(4)" ::: "memory"); }
        else            { asm volatile("s_waitcnt vmcnt(0)" ::: "memory"); }
        SCHED0();
        BAR();
    }

#pragma unroll
    for (int mt = 0; mt < 4; mt++)
#pragma unroll
        for (int nt = 0; nt < 4; nt++) {
            int c = n0 + wn * 64 + nt * 16 + m15;
#pragma unroll
            for (int r = 0; r < 4; r++) {
                int mrow = m0 + wm * 64 + mt * 16 + quad * 4 + r;
                C[(size_t)mrow * N + c] = acc[mt][nt][r];
            }
        }
}

// ---------------------------------------------------------------------------
// Flash attention v6: single-phase iteration (1 barrier per 64-key tile).
// Per iter: {16 K ds_reads | stage K,V(t+1) issue-early | QK MFMA |
//            16 V ds_reads (hide under softmax) | softmax + cvt_pk pack |
//            PV MFMA | vmcnt(0) drain (loads ~1 phase old) | barrier}.
// WAR: iter t stages into [1-cur], whose last ds_reads (iter t-1) completed
// before iter t-1's end barrier. lgkm waits left to compiler (fine-grained).
// ---------------------------------------------------------------------------
__device__ __forceinline__ void stgK64(const u16* kB, u16* Kl, int kt, int tid) {
    int keyc = tid >> 4, ch = tid & 15;
    const u16* g = kB + (size_t)(kt + keyc) * LDQKV + (ch ^ keyc) * 8;
    u16* l = Kl + tid * 8;
#pragma unroll
    for (int j = 0; j < 4; j++) {
        gl16(g, l);
        g += (size_t)16 * LDQKV;
        l += 2048;
    }
}
__device__ __forceinline__ void stgV64(const u16* vB, u16* Vl, int kt, int tid) {
    int hdc = tid >> 3, ch = tid & 7;
    const u16* g = vB + (size_t)hdc * T_ + kt + (ch ^ (hdc & 7)) * 8;
    u16* l = Vl + tid * 8;
#pragma unroll
    for (int j = 0; j < 4; j++) {
        gl16(g, l);
        g += (size_t)32 * T_;
        l += 2048;
    }
}

__global__ __launch_bounds__(256) void flash_k(const u16* __restrict__ qkv,
                                               const u16* __restrict__ vtb,
                                               u16* __restrict__ yb) {
    __shared__ __align__(16) u16 Kl[2][64 * 128];   // 32 KB
    __shared__ __align__(16) u16 Vl[2][128 * 64];   // 32 KB -> 64 KB total: 2 blocks/CU
    int h = blockIdx.y, b = blockIdx.z;
    int kv = h / REP_;
    int tid = threadIdx.x;
    int lane = tid & 63, wave = tid >> 6;
    int m15 = lane & 15, quad = lane >> 4;
    int sw8 = m15 & 7;
    const u16* kB = qkv + (size_t)b * T_ * LDQKV + 2048 + kv * HD_;
    const u16* vB = vtb + ((size_t)(b * NKV_ + kv)) * HD_ * T_;
    const float scale2 = 0.1275173723f;  // 1/sqrt(128) * log2(e)
    const float M0b = 8.0f;              // fixed max (exp2 domain)
    const float NEG = -3.0e38f;

    for (int p = 0; p < 2; p++) {
        int qt = (p == 0) ? (int)blockIdx.x : (31 - (int)blockIdx.x);
        int qt0 = qt * 64;
        int q_i = qt0 + wave * 16 + m15;     // this lane's query (col of S^T)
        const u16* qp = qkv + (size_t)(b * T_ + q_i) * LDQKV + h * HD_ + quad * 8;
        bf16x8v qf[4];
#pragma unroll
        for (int kc = 0; kc < 4; kc++) qf[kc] = load8(qp + kc * 32);
        f32x4v o[8] = {};
        f32x4v lacc = {};
        int NT = qt + 1;

        // prologue: stage tile0 only; vmcnt(0) also drains qf loads + prior
        // pass's epilogue stores (older).
        stgK64(kB, &Kl[0][0], 0, tid);
        stgV64(vB, &Vl[0][0], 0, tid);
        asm volatile("s_waitcnt vmcnt(0)" ::: "memory");
        SCHED0();
        BAR();

        for (int it = 0; it < NT; it++) {
            int cur = it & 1;
            int kt = it * 64;
            const u16* Kc = &Kl[cur][0];
            const u16* Vc = &Vl[cur][0];

            // K fragments for this tile
            bf16x8v kf[4][4];
#pragma unroll
            for (int nt = 0; nt < 4; nt++) {
                const u16* kls = Kc + (nt * 16 + m15) * 128;
#pragma unroll
                for (int kc = 0; kc < 4; kc++)
                    kf[nt][kc] = load8(kls + (((kc * 4 + quad) ^ m15) * 8));
            }
            // issue next tile's staging early (waited at end of this iter)
            if (it + 1 < NT) {
                stgK64(kB, &Kl[1 - cur][0], kt + 64, tid);
                stgV64(vB, &Vl[1 - cur][0], kt + 64, tid);
            }
            SCHED0();
            // QK^T on 64 keys (compiler inserts fine-grained lgkm waits)
            f32x4v s4[4] = {};
            PRIO(1);
#pragma unroll
            for (int nt = 0; nt < 4; nt++)
#pragma unroll
                for (int kc = 0; kc < 4; kc++)
                    s4[nt] = __builtin_amdgcn_mfma_f32_16x16x32_bf16(
                        kf[nt][kc], qf[kc], s4[nt], 0, 0, 0);
            PRIO(0);
            // V fragments (latency hides under softmax)
            bf16x8v vf[2][8];
#pragma unroll
            for (int c = 0; c < 2; c++)
#pragma unroll
                for (int dt = 0; dt < 8; dt++)
                    vf[c][dt] = load8(Vc + (dt * 16 + m15) * 64 + (((c * 4 + quad) ^ sw8) * 8));
            // causal mask (last iter only): key > q
            if (kt + 64 > qt0) {
#pragma unroll
                for (int nt = 0; nt < 4; nt++) {
                    int key = kt + nt * 16 + quad * 4;
#pragma unroll
                    for (int r = 0; r < 4; r++)
                        if (key + r > q_i) s4[nt][r] = NEG;
                }
            }
            // fixed-max exp2 + l accumulation (no shuffles, no rescale)
#pragma unroll
            for (int nt = 0; nt < 4; nt++) {
#pragma unroll
                for (int r = 0; r < 4; r++)
                    s4[nt][r] = exp2f(fmaf(s4[nt][r], scale2, -M0b));
                lacc += s4[nt];
            }
            // pack P to bf16 B-frags: v_cvt_pk_bf16_f32 (1 instr per pair)
            bf16x8v pf[2];
#pragma unroll
            for (int c = 0; c < 2; c++) {
                unsigned int w[4];
                w[0] = cvtpk(s4[2 * c][0], s4[2 * c][1]);
                w[1] = cvtpk(s4[2 * c][2], s4[2 * c][3]);
                w[2] = cvtpk(s4[2 * c + 1][0], s4[2 * c + 1][1]);
                w[3] = cvtpk(s4[2 * c + 1][2], s4[2 * c + 1][3]);
                __builtin_memcpy(&pf[c], w, 16);
            }
            // PV
            PRIO(1);
#pragma unroll
            for (int c = 0; c < 2; c++)
#pragma unroll
                for (int dt = 0; dt < 8; dt++)
                    o[dt] = __builtin_amdgcn_mfma_f32_16x16x32_bf16(
                        vf[c][dt], pf[c], o[dt], 0, 0, 0);
            PRIO(0);
            // drain this iter's prefetch (issued ~1 phase ago) and sync
            if (it + 1 < NT) { asm volatile("s_waitcnt vmcnt(0)" ::: "memory"); }
            SCHED0();
            BAR();
        }

        // epilogue: l = sum of this lane's 4 partials, then across quads
        float l = lacc[0] + lacc[1] + lacc[2] + lacc[3];
        l += __shfl_xor(l, 16, 64);
        l += __shfl_xor(l, 32, 64);
        float inv = 1.f / l;
        u16* yp = yb + (size_t)(b * T_ + q_i) * C_ + h * HD_ + quad * 4;
#pragma unroll
        for (int dt = 0; dt < 8; dt++) {
            ushort4 pk;
            pk.x = f2bf(o[dt][0] * inv);
            pk.y = f2bf(o[dt][1] * inv);
            pk.z = f2bf(o[dt][2] * inv);
            pk.w = f2bf(o[dt][3] * inv);
            *reinterpret_cast<ushort4*>(yp + dt * 16) = pk;
        }
    }
}

// ---------------------------------------------------------------------------
extern "C" void kernel_launch(void* const* d_in, const int* in_sizes, int n_in,
                              void* d_out, int out_size, void* d_ws, size_t ws_size,
                              hipStream_t stream) {
    const float* x  = (const float*)d_in[0];
    const float* Wq = (const float*)d_in[1];
    const float* Wk = (const float*)d_in[2];
    const float* Wv = (const float*)d_in[3];
    const float* Wo = (const float*)d_in[4];
    const float* fc = (const float*)d_in[5];
    const float* fs = (const float*)d_in[6];
    float* out = (float*)d_out;

    char* ws = (char*)d_ws;
    u16* WqkvT = (u16*)(ws);                    // [3072][2048] bf16, 12.58 MB
    u16* WoT   = (u16*)(ws + 12582912);         // [2048][2048] bf16,  8.39 MB
    u16* xb    = (u16*)(ws + 20971520);         // [4096][2048] bf16, 16.78 MB
    u16* qkvb  = (u16*)(ws + 37748736);         // [4096][3072] bf16, 25.17 MB
    u16* vtb   = (u16*)(ws + 62914560);         // [B][512][T]  bf16,  4.19 MB
    u16* yb    = (u16*)(ws + 67108864);         // [4096][2048] bf16, 16.78 MB

    const int M = B_ * T_;

    int n4 = (M * C_) / 4;
    cvt_f32_bf16<<<n4 / 256, 256, 0, stream>>>(x, xb, n4);

    dim3 tb(32, 8);
    xpose_f32_bf16<<<dim3(C_ / 32, C_ / 32), tb, 0, stream>>>(Wq, WqkvT, C_, C_);
    xpose_f32_bf16<<<dim3((NKV_ * HD_) / 32, C_ / 32), tb, 0, stream>>>(Wk, WqkvT + 2048 * 2048, C_, NKV_ * HD_);
    xpose_f32_bf16<<<dim3((NKV_ * HD_) / 32, C_ / 32), tb, 0, stream>>>(Wv, WqkvT + 2560 * 2048, C_, NKV_ * HD_);
    xpose_f32_bf16<<<dim3(C_ / 32, C_ / 32), tb, 0, stream>>>(Wo, WoT, C_, C_);

    // fused QKV projection + in-epilogue RoPE; V pre-transposed into vtb
    // grid = (3072/192)*(4096/256) = 256 workgroups = full machine
    gemm_qkv<<<dim3((LDQKV / 192) * (M / 256)), 512, 0, stream>>>(xb, WqkvT, qkvb, vtb, fc, fs, M, LDQKV, C_);

    flash_k<<<dim3(T_ / 128, NH_, B_), 256, 0, stream>>>(qkvb, vtb, yb);

    // grid = (2048/256)*(4096/128) = 256 workgroups = full machine
    gemm_out<<<dim3((C_ / 256) * (M / 128)), 512, 0, stream>>>(yb, WoT, out, M, C_, C_);
}